// Round 7
// baseline (223.647 us; speedup 1.0000x reference)
//
#include <hip/hip_runtime.h>
#include <hip/hip_bf16.h>

#define N_NODES 16384
#define E_EDGES 131072
#define F_IN 6
#define S_DIM 4
#define G_GRAPHS 256
#define H_DIM 30
#define C1 32
#define C2 64
#define C3 32

typedef __attribute__((ext_vector_type(2))) _Float16 f16x2;
typedef __attribute__((ext_vector_type(2))) __fp16 fp16v2;
typedef __attribute__((ext_vector_type(8))) _Float16 f16x8;
typedef __attribute__((ext_vector_type(4))) float f32x4;

// f32 -> f16 bits (RNE via v_cvt_f16_f32)
__device__ __forceinline__ unsigned short f2h(float f) {
    union { _Float16 h; unsigned short s; } c; c.h = (_Float16)f; return c.s;
}

// pack two f32 -> packed f16 pair (one v_cvt_pkrtz_f16_f32)
__device__ __forceinline__ unsigned pkh2(float a, float b) {
    union { fp16v2 h; unsigned u; } c; c.h = __builtin_amdgcn_cvt_pkrtz(a, b); return c.u;
}

// duplicate low/high f16 half into both halves (one v_perm_b32)
__device__ __forceinline__ unsigned dup_lo(unsigned v) {
    return __builtin_amdgcn_perm(v, v, 0x01000100u);
}
__device__ __forceinline__ unsigned dup_hi(unsigned v) {
    return __builtin_amdgcn_perm(v, v, 0x03020302u);
}

// packed f16 multiply (one v_pk_mul_f16)
__device__ __forceinline__ unsigned pkmul(unsigned a, unsigned b) {
    union { unsigned u; f16x2 h; } x, y, r;
    x.u = a; y.u = b; r.h = x.h * y.h; return r.u;
}

// pack two f32 -> (bf16 lo, bf16 hi)  [message format, baseline-proven]
__device__ __forceinline__ unsigned pack2(float a, float b) {
    unsigned ua = __float_as_uint(a) + 0x8000u;
    unsigned ub = __float_as_uint(b) + 0x8000u;
    return __builtin_amdgcn_perm(ub, ua, 0x07060302u);
}

// ---------------------------------------------------------------------------
// prep: tables only (wbt1/wbt2 kernel-net weights, w1bt1/w1bt2 MLP layer-2
// weights+bias, all f16 B-fragment layout). 75776 threads = 296 blocks.
// ---------------------------------------------------------------------------
__global__ __launch_bounds__(256) void prep(
    const float* __restrict__ wk2, const float* __restrict__ bk2,
    const float* __restrict__ wk1, const float* __restrict__ bk1,
    const float* __restrict__ w1h2, const float* __restrict__ b1h2,
    const float* __restrict__ w1h1, const float* __restrict__ b1h1,
    short* __restrict__ wbt2, short* __restrict__ wbt1,
    short* __restrict__ w1bt2, short* __restrict__ w1bt1)
{
    const int gtid = blockIdx.x * 256 + threadIdx.x;
    if (gtid < 65536) {
        const int idx = gtid;
        const int j = idx & 7, kq = (idx >> 3) & 3, n = (idx >> 5) & 15;
        const int nt = (idx >> 9) & 3, kc = idx >> 11;
        const int c1 = kq * 8 + j, c2 = nt * 16 + n;
        float v = (kc < 30) ? wk2[kc * 2048 + c1 * 64 + c2]
                            : ((kc == 30) ? bk2[c1 * 64 + c2] : 0.f);
        wbt2[idx] = (short)f2h(v);
    } else if (gtid < 73728) {
        const int i2 = gtid - 65536;
        const int j = i2 & 7, kq = (i2 >> 3) & 3, n = (i2 >> 5) & 15;
        const int nt = (i2 >> 9) & 1, kc = i2 >> 10;
        const int h = kc * 4 + kq, c1 = nt * 16 + n;
        float v = 0.f;
        if (j < 6) {
            if (h < 30) v = wk1[h * 192 + j * 32 + c1];
            else if (h == 30) v = bk1[j * 32 + c1];
        }
        wbt1[i2] = (short)f2h(v);
    } else if (gtid < 74752) {
        // w1bt2[col*32 + k] = B[k][col]: k<30 -> w1[k][col], k==30 -> b1[col]
        const int i3 = gtid - 73728;
        const int col = i3 >> 5, k = i3 & 31;
        float v = 0.f;
        if (col < 30) {
            if (k < 30) v = w1h2[k * 30 + col];
            else if (k == 30) v = b1h2[col];
        }
        w1bt2[i3] = (short)f2h(v);
    } else {
        const int i4 = gtid - 74752;
        const int col = i4 >> 5, k = i4 & 31;
        float v = 0.f;
        if (col < 30) {
            if (k < 30) v = w1h1[k * 30 + col];
            else if (k == 30) v = b1h1[col];
        }
        w1bt1[i4] = (short)f2h(v);
    }
}

// ---------------------------------------------------------------------------
// csr_scan: fused tgt-histogram (packed u16 LDS atomics, 2 counters/u32)
// + exclusive scan over N=16384. Single block, 1024 threads.
// Replaces: deg global array + deg memset + prep's 131072 global atomics.
// ---------------------------------------------------------------------------
__global__ __launch_bounds__(1024) void csr_scan(
    const int* __restrict__ tgt, int* __restrict__ off, int* __restrict__ cursor)
{
    __shared__ unsigned hist[8192];   // 16384 u16 counters packed, 32 KB
    __shared__ int s[1024];
    const int t = threadIdx.x;
    #pragma unroll
    for (int i = 0; i < 8; ++i) hist[t + i * 1024] = 0u;
    __syncthreads();
    // histogram: 128 coalesced tgt reads per thread
    for (int i = 0; i < 128; ++i) {
        const int v = tgt[i * 1024 + t];
        atomicAdd(&hist[v >> 1], 1u << ((v & 1) * 16));
    }
    __syncthreads();
    // each thread owns 16 nodes = 8 packed words
    const int base = t * 16;
    int loc[16]; int sum = 0;
    #pragma unroll
    for (int i = 0; i < 8; ++i) {
        const unsigned pw = hist[t * 8 + i];
        const int c0 = (int)(pw & 0xFFFFu), c1 = (int)(pw >> 16);
        loc[2 * i] = sum;     sum += c0;
        loc[2 * i + 1] = sum; sum += c1;
    }
    s[t] = sum;
    __syncthreads();
    int v = sum;
    for (int d = 1; d < 1024; d <<= 1) {
        const int add = (t >= d) ? s[t - d] : 0;
        __syncthreads();
        v += add; s[t] = v;
        __syncthreads();
    }
    const int pre = v - sum;
    #pragma unroll
    for (int i = 0; i < 16; ++i) {
        const int o = pre + loc[i];
        off[base + i] = o; cursor[base + i] = o;
    }
    if (t == 1023) off[N_NODES] = E_EDGES;
}

// ---------------------------------------------------------------------------
// ECC1 + fused CSR permute (unchanged from round 6 — verified passing).
// ---------------------------------------------------------------------------
__global__ __launch_bounds__(256, 2) void ecc1_mfma(
    const float* __restrict__ x, const float* __restrict__ e,
    const int* __restrict__ src, const int* __restrict__ tgt,
    const float* __restrict__ gcn_w,
    const float* __restrict__ w0, const float* __restrict__ b0,
    const short* __restrict__ w1bt, const short* __restrict__ wbt1,
    int* __restrict__ cursor, int* __restrict__ perm,
    int* __restrict__ srcp, float* __restrict__ gwp,
    unsigned* __restrict__ msg1)
{
    __shared__ unsigned short s_h1b[256 * 40];
    __shared__ unsigned short s_xb[256 * 8];
    __shared__ int s_perm[256];
    __shared__ float s_w0[120], s_b0[30];

    const int t = threadIdx.x;
    const int tile = blockIdx.x * 256;
    for (int i = t; i < 120; i += 256) s_w0[i] = w0[i];
    if (t < 30) s_b0[t] = b0[t];
    __syncthreads();

    // ---- phase A: CSR permute + MLP layer-1 + h0/x staging (f16) ----
    {
        const int eid = tile + t;
        const int sv = src[eid];
        const int p = atomicAdd(&cursor[tgt[eid]], 1);
        s_perm[t] = p;
        perm[eid] = p;
        srcp[p] = sv;
        gwp[p] = gcn_w[eid];

        const float4 ev = *(const float4*)(e + eid * 4);
        float h0[30];
        #pragma unroll
        for (int j = 0; j < 30; ++j) {
            float v = ev.x * s_w0[j] + ev.y * s_w0[30 + j]
                    + ev.z * s_w0[60 + j] + ev.w * s_w0[90 + j] + s_b0[j];
            h0[j] = fmaxf(v, 0.f);
        }
        unsigned hw[16];
        #pragma unroll
        for (int i = 0; i < 15; ++i) hw[i] = pkh2(h0[2 * i], h0[2 * i + 1]);
        hw[15] = pkh2(1.0f, 0.f);
        uint4* hb = (uint4*)&s_h1b[t * 40];
        hb[0] = make_uint4(hw[0], hw[1], hw[2], hw[3]);
        hb[1] = make_uint4(hw[4], hw[5], hw[6], hw[7]);
        hb[2] = make_uint4(hw[8], hw[9], hw[10], hw[11]);
        hb[3] = make_uint4(hw[12], hw[13], hw[14], hw[15]);

        const float2* xp = (const float2*)(x + (size_t)sv * F_IN);
        const float2 a = xp[0], b2 = xp[1], c2 = xp[2];
        *(uint4*)&s_xb[t * 8] =
            make_uint4(pkh2(a.x, a.y), pkh2(b2.x, b2.y), pkh2(c2.x, c2.y), 0u);
    }
    __syncthreads();

    const int wv = t >> 6, lane = t & 63;
    const int n = lane & 15, quad = lane >> 4;
    const int e0 = wv * 64;

    // ---- MLP layer-2 via MFMA: h1 = relu(h0 @ w1 + b1), in-place (f16) ----
    {
        const f16x8 wf0 = *(const f16x8*)(w1bt + n * 32 + quad * 8);
        const f16x8 wf1 = *(const f16x8*)(w1bt + (16 + n) * 32 + quad * 8);
        #pragma unroll
        for (int m = 0; m < 4; ++m) {
            const f16x8 a0 = *(const f16x8*)&s_h1b[(e0 + m * 16 + n) * 40 + quad * 8];
            f32x4 c0 = {0.f, 0.f, 0.f, 0.f}, c1 = {0.f, 0.f, 0.f, 0.f};
            c0 = __builtin_amdgcn_mfma_f32_16x16x32_f16(a0, wf0, c0, 0, 0, 0);
            c1 = __builtin_amdgcn_mfma_f32_16x16x32_f16(a0, wf1, c1, 0, 0, 0);
            #pragma unroll
            for (int r = 0; r < 4; ++r) {
                const int row = e0 + m * 16 + quad * 4 + r;
                s_h1b[row * 40 + n] = f2h(fmaxf(c0[r], 0.f));
                s_h1b[row * 40 + 16 + n] = (n == 14) ? (unsigned short)0x3C00
                                                     : f2h(fmaxf(c1[r], 0.f));
            }
        }
    }
    __syncthreads();

    // ---- main MFMA: A = dup(h) * packed-x ----
    unsigned xpk[4][3];
    #pragma unroll
    for (int m = 0; m < 4; ++m) {
        const uint4 xv = *(const uint4*)&s_xb[(e0 + m * 16 + n) * 8];
        xpk[m][0] = xv.x; xpk[m][1] = xv.y; xpk[m][2] = xv.z;
    }

    f32x4 acc[4][2];
    #pragma unroll
    for (int m = 0; m < 4; ++m) {
        acc[m][0] = (f32x4){0.f, 0.f, 0.f, 0.f};
        acc[m][1] = (f32x4){0.f, 0.f, 0.f, 0.f};
    }

    #pragma unroll
    for (int kc = 0; kc < 8; ++kc) {
        f16x8 bfr[2];
        #pragma unroll
        for (int nt = 0; nt < 2; ++nt)
            bfr[nt] = *(const f16x8*)(wbt1 + (((kc * 2 + nt) * 16 + n) << 5) + quad * 8);
        #pragma unroll
        for (int m = 0; m < 4; ++m) {
            const unsigned hv = s_h1b[(e0 + m * 16 + n) * 40 + kc * 4 + quad];
            const unsigned hh = dup_lo(hv);
            union { unsigned u[4]; f16x8 v; } af;
            af.u[0] = pkmul(hh, xpk[m][0]);
            af.u[1] = pkmul(hh, xpk[m][1]);
            af.u[2] = pkmul(hh, xpk[m][2]);
            af.u[3] = 0u;
            acc[m][0] = __builtin_amdgcn_mfma_f32_16x16x32_f16(af.v, bfr[0], acc[m][0], 0, 0, 0);
            acc[m][1] = __builtin_amdgcn_mfma_f32_16x16x32_f16(af.v, bfr[1], acc[m][1], 0, 0, 0);
        }
    }

    #pragma unroll
    for (int m = 0; m < 4; ++m)
        #pragma unroll
        for (int r = 0; r < 4; ++r) {
            const int p = s_perm[e0 + m * 16 + quad * 4 + r];
            msg1[p * 16 + n] = pack2(acc[m][0][r], acc[m][1][r]);
        }
}

// gather msg1 (SEQUENTIAL, permuted layout) + node update 1 -> x1
__global__ __launch_bounds__(256) void gather1(
    const unsigned* __restrict__ msg1, const int* __restrict__ off,
    const float* __restrict__ x,
    const float* __restrict__ root, const float* __restrict__ bias,
    float* __restrict__ x1)
{
    __shared__ float s_root[192];
    __shared__ float s_b[32];
    const int t = threadIdx.x;
    if (t < 192) s_root[t] = root[t];
    if (t < 32) s_b[t] = bias[t];
    __syncthreads();
    const int v = blockIdx.x * 16 + (t >> 4);
    const int n = t & 15;
    const int o0 = off[v], o1 = off[v + 1];
    float sa = 0.f, sb = 0.f;
    for (int j = o0; j < o1; ++j) {
        const unsigned u = msg1[j * 16 + n];
        sa += __uint_as_float(u << 16);
        sb += __uint_as_float(u & 0xFFFF0000u);
    }
    const float* xr = x + (size_t)v * F_IN;
    float ra = s_b[n], rb = s_b[16 + n];
    #pragma unroll
    for (int f = 0; f < 6; ++f) {
        const float xv = xr[f];
        ra += xv * s_root[f * 32 + n];
        rb += xv * s_root[f * 32 + 16 + n];
    }
    x1[v * 32 + n] = fmaxf(sa + ra, 0.f);
    x1[v * 32 + 16 + n] = fmaxf(sb + rb, 0.f);
}

// ---------------------------------------------------------------------------
// ECC2 (unchanged from round 6 — verified passing).
// ---------------------------------------------------------------------------
__global__ __launch_bounds__(256, 2) void ecc2_mfma(
    const float* __restrict__ x1, const float* __restrict__ e,
    const int* __restrict__ src, const int* __restrict__ perm,
    const float* __restrict__ w0, const float* __restrict__ b0,
    const short* __restrict__ w1bt, const short* __restrict__ wbt2,
    unsigned* __restrict__ msg2)
{
    __shared__ unsigned short s_h1b[256 * 40];
    __shared__ unsigned short s_x1b[256 * 40];
    __shared__ int s_perm[256];
    __shared__ float s_w0[120], s_b0[30];

    const int t = threadIdx.x;
    const int tile = blockIdx.x * 256;
    for (int i = t; i < 120; i += 256) s_w0[i] = w0[i];
    if (t < 30) s_b0[t] = b0[t];
    __syncthreads();

    // ---- phase A ----
    {
        const int eid = tile + t;
        s_perm[t] = perm[eid];
        const float4 ev = *(const float4*)(e + eid * 4);
        float h0[30];
        #pragma unroll
        for (int j = 0; j < 30; ++j) {
            float v = ev.x * s_w0[j] + ev.y * s_w0[30 + j]
                    + ev.z * s_w0[60 + j] + ev.w * s_w0[90 + j] + s_b0[j];
            h0[j] = fmaxf(v, 0.f);
        }
        unsigned hw[16];
        #pragma unroll
        for (int i = 0; i < 15; ++i) hw[i] = pkh2(h0[2 * i], h0[2 * i + 1]);
        hw[15] = pkh2(1.0f, 0.f);
        uint4* hb = (uint4*)&s_h1b[t * 40];
        hb[0] = make_uint4(hw[0], hw[1], hw[2], hw[3]);
        hb[1] = make_uint4(hw[4], hw[5], hw[6], hw[7]);
        hb[2] = make_uint4(hw[8], hw[9], hw[10], hw[11]);
        hb[3] = make_uint4(hw[12], hw[13], hw[14], hw[15]);

        const float* xp = x1 + (size_t)src[eid] * C1;
        uint4* xb = (uint4*)&s_x1b[t * 40];
        #pragma unroll
        for (int q = 0; q < 4; ++q) {
            const float4 v0 = *(const float4*)(xp + q * 8);
            const float4 v1 = *(const float4*)(xp + q * 8 + 4);
            xb[q] = make_uint4(pkh2(v0.x, v0.y), pkh2(v0.z, v0.w),
                               pkh2(v1.x, v1.y), pkh2(v1.z, v1.w));
        }
    }
    __syncthreads();

    const int wv = t >> 6, lane = t & 63;
    const int n = lane & 15, quad = lane >> 4;
    const int e0 = wv * 64;

    // ---- MLP layer-2 via MFMA, in-place (f16) ----
    {
        const f16x8 wf0 = *(const f16x8*)(w1bt + n * 32 + quad * 8);
        const f16x8 wf1 = *(const f16x8*)(w1bt + (16 + n) * 32 + quad * 8);
        #pragma unroll
        for (int m = 0; m < 4; ++m) {
            const f16x8 a0 = *(const f16x8*)&s_h1b[(e0 + m * 16 + n) * 40 + quad * 8];
            f32x4 c0 = {0.f, 0.f, 0.f, 0.f}, c1 = {0.f, 0.f, 0.f, 0.f};
            c0 = __builtin_amdgcn_mfma_f32_16x16x32_f16(a0, wf0, c0, 0, 0, 0);
            c1 = __builtin_amdgcn_mfma_f32_16x16x32_f16(a0, wf1, c1, 0, 0, 0);
            #pragma unroll
            for (int r = 0; r < 4; ++r) {
                const int row = e0 + m * 16 + quad * 4 + r;
                s_h1b[row * 40 + n] = f2h(fmaxf(c0[r], 0.f));
                s_h1b[row * 40 + 16 + n] = (n == 14) ? (unsigned short)0x3C00
                                                     : f2h(fmaxf(c1[r], 0.f));
            }
        }
    }
    __syncthreads();

    // ---- main MFMA: A = dup(h) * packed-x1 ----
    unsigned xpk[4][4];
    #pragma unroll
    for (int m = 0; m < 4; ++m) {
        const uint4 xv = *(const uint4*)&s_x1b[(e0 + m * 16 + n) * 40 + quad * 8];
        xpk[m][0] = xv.x; xpk[m][1] = xv.y; xpk[m][2] = xv.z; xpk[m][3] = xv.w;
    }

    f32x4 acc[4][4];
    #pragma unroll
    for (int m = 0; m < 4; ++m)
        #pragma unroll
        for (int nt = 0; nt < 4; ++nt) acc[m][nt] = (f32x4){0.f, 0.f, 0.f, 0.f};

    #pragma unroll
    for (int kb = 0; kb < 4; ++kb) {
        unsigned hqa[4][4];
        #pragma unroll
        for (int m = 0; m < 4; ++m)
            *(uint4*)&hqa[m][0] = *(const uint4*)&s_h1b[(e0 + m * 16 + n) * 40 + kb * 8];
        #pragma unroll
        for (int k8 = 0; k8 < 8; ++k8) {
            const int kc = kb * 8 + k8;
            f16x8 bfr[4];
            #pragma unroll
            for (int nt = 0; nt < 4; ++nt)
                bfr[nt] = *(const f16x8*)(wbt2 + (((kc * 4 + nt) * 16 + n) << 5) + quad * 8);
            #pragma unroll
            for (int m = 0; m < 4; ++m) {
                const unsigned hu = hqa[m][k8 >> 1];
                const unsigned hh = (k8 & 1) ? dup_hi(hu) : dup_lo(hu);
                union { unsigned u[4]; f16x8 v; } af;
                af.u[0] = pkmul(hh, xpk[m][0]);
                af.u[1] = pkmul(hh, xpk[m][1]);
                af.u[2] = pkmul(hh, xpk[m][2]);
                af.u[3] = pkmul(hh, xpk[m][3]);
                #pragma unroll
                for (int nt = 0; nt < 4; ++nt)
                    acc[m][nt] = __builtin_amdgcn_mfma_f32_16x16x32_f16(af.v, bfr[nt], acc[m][nt], 0, 0, 0);
            }
        }
    }

    #pragma unroll
    for (int m = 0; m < 4; ++m)
        #pragma unroll
        for (int r = 0; r < 4; ++r) {
            const int p = s_perm[e0 + m * 16 + quad * 4 + r];
            uint2 val;
            val.x = pack2(acc[m][0][r], acc[m][1][r]);
            val.y = pack2(acc[m][2][r], acc[m][3][r]);
            *(uint2*)&msg2[p * 32 + n * 2] = val;
        }
}

// gather msg2 (sequential) + node update 2 + xw = x2 @ gcn_W -> xw
// Also zeroes `out` (blocks 0..31) so no separate memset dispatch is needed.
__global__ __launch_bounds__(256) void gather2(
    const unsigned* __restrict__ msg2, const int* __restrict__ off,
    const float* __restrict__ x1,
    const float* __restrict__ root, const float* __restrict__ bias,
    const float* __restrict__ W, float* __restrict__ xw,
    float* __restrict__ out)
{
    __shared__ float s_root[2048], s_W[2048], s_b[64];
    __shared__ float s_x2[8][68];
    __shared__ float s_x1v[256];
    const int t = threadIdx.x;
    if (blockIdx.x < 32) out[blockIdx.x * 256 + t] = 0.f;   // G*C3 = 8192
    for (int i = t; i < 2048; i += 256) { s_root[i] = root[i]; s_W[i] = W[i]; }
    if (t < 64) s_b[t] = bias[t];
    s_x1v[t] = x1[blockIdx.x * 256 + t];
    __syncthreads();

    const int lv = t >> 5;
    const int v = blockIdx.x * 8 + lv;
    const int j5 = t & 31;
    const int n = j5 >> 1, p = j5 & 1;
    const int ca = p * 32 + n, cb = p * 32 + 16 + n;
    const int o0 = off[v], o1 = off[v + 1];
    float sa = 0.f, sb = 0.f;
    for (int j = o0; j < o1; ++j) {
        const unsigned u = msg2[j * 32 + j5];
        sa += __uint_as_float(u << 16);
        sb += __uint_as_float(u & 0xFFFF0000u);
    }
    float ra = s_b[ca], rb = s_b[cb];
    #pragma unroll 8
    for (int k = 0; k < 32; ++k) {
        const float xv = s_x1v[lv * 32 + k];
        ra += xv * s_root[k * 64 + ca];
        rb += xv * s_root[k * 64 + cb];
    }
    s_x2[lv][ca] = fmaxf(sa + ra, 0.f);
    s_x2[lv][cb] = fmaxf(sb + rb, 0.f);
    __syncthreads();

    float av = 0.f;
    #pragma unroll 8
    for (int k = 0; k < 64; ++k) av += s_x2[lv][k] * s_W[k * 32 + j5];
    xw[v * 32 + j5] = av;
}

// GCN gather + relu + global pool. seg is sorted: when all 8 nodes of the
// block share one graph (common case), LDS-reduce and emit ONE atomicAdd
// per channel instead of 8 -> ~4x fewer global atomics, lower collision depth.
__global__ __launch_bounds__(256) void gcn_pool(
    const float* __restrict__ xw, const int* __restrict__ off,
    const int* __restrict__ srcp, const float* __restrict__ gwp,
    const float* __restrict__ gw, const float* __restrict__ gb,
    const int* __restrict__ seg, float* __restrict__ out)
{
    __shared__ float s_gb[32];
    __shared__ float s_vals[8][32];
    __shared__ int s_seg[8];
    const int t = threadIdx.x;
    const int lv = t >> 5;
    const int c = t & 31;
    const int v = blockIdx.x * 8 + lv;
    if (t < 32) s_gb[t] = gb[t];
    if (c == 0) s_seg[lv] = seg[v];
    __syncthreads();
    const int o0 = off[v], o1 = off[v + 1];
    float s = gw[E_EDGES + v] * xw[v * 32 + c];   // self loop
    for (int j = o0; j < o1; ++j)
        s += gwp[j] * xw[srcp[j] * 32 + c];
    const float val = fmaxf(s + s_gb[c], 0.f);
    if (s_seg[0] == s_seg[7]) {          // block-uniform graph (seg sorted)
        s_vals[lv][c] = val;
        __syncthreads();
        if (lv == 0) {
            float acc = s_vals[0][c] + s_vals[1][c] + s_vals[2][c] + s_vals[3][c]
                      + s_vals[4][c] + s_vals[5][c] + s_vals[6][c] + s_vals[7][c];
            atomicAdd(&out[s_seg[0] * 32 + c], acc);
        }
    } else {
        atomicAdd(&out[s_seg[lv] * 32 + c], val);
    }
}

extern "C" void kernel_launch(void* const* d_in, const int* in_sizes, int n_in,
                              void* d_out, int out_size, void* d_ws, size_t ws_size,
                              hipStream_t stream)
{
    const float* x       = (const float*)d_in[0];
    const float* e       = (const float*)d_in[1];
    const int*   src     = (const int*)d_in[2];
    const int*   tgt     = (const int*)d_in[3];
    const int*   seg     = (const int*)d_in[4];
    const float* gcn_w   = (const float*)d_in[7];
    const float* e1_w0   = (const float*)d_in[8];
    const float* e1_b0   = (const float*)d_in[9];
    const float* e1_w1   = (const float*)d_in[10];
    const float* e1_b1   = (const float*)d_in[11];
    const float* e1_wk   = (const float*)d_in[12];
    const float* e1_bk   = (const float*)d_in[13];
    const float* e1_root = (const float*)d_in[14];
    const float* e1_bias = (const float*)d_in[15];
    const float* e2_w0   = (const float*)d_in[16];
    const float* e2_b0   = (const float*)d_in[17];
    const float* e2_w1   = (const float*)d_in[18];
    const float* e2_b1   = (const float*)d_in[19];
    const float* e2_wk   = (const float*)d_in[20];
    const float* e2_bk   = (const float*)d_in[21];
    const float* e2_root = (const float*)d_in[22];
    const float* e2_bias = (const float*)d_in[23];
    const float* gcn_W   = (const float*)d_in[24];
    const float* gcn_b   = (const float*)d_in[25];
    float* out = (float*)d_out;

    float*    ws    = (float*)d_ws;
    float*    x1    = ws;                                   // [N,32]
    float*    xw    = x1 + (size_t)N_NODES * 32;            // [N,32]
    unsigned* msg1  = (unsigned*)(xw + (size_t)N_NODES * 32);   // E*16 u32
    unsigned* msg2  = msg1 + (size_t)E_EDGES * 16;          // E*32 u32
    short*    wbt2  = (short*)(msg2 + (size_t)E_EDGES * 32);// 65536 f16
    short*    wbt1  = wbt2 + 65536;                         // 8192 f16
    short*    w1bt2 = wbt1 + 8192;                          // 1024 f16
    short*    w1bt1 = w1bt2 + 1024;                         // 1024 f16
    int*      off   = (int*)(w1bt1 + 1024);                 // N+1 (+pad)
    int*      cursor= off + N_NODES + 16;                   // N
    int*      perm  = cursor + N_NODES;                     // E
    int*      srcp  = perm + E_EDGES;                       // E
    float*    gwp   = (float*)(srcp + E_EDGES);             // E

    csr_scan<<<1, 1024, 0, stream>>>(tgt, off, cursor);
    prep<<<296, 256, 0, stream>>>(e2_wk, e2_bk, e1_wk, e1_bk,
        e2_w1, e2_b1, e1_w1, e1_b1, wbt2, wbt1, w1bt2, w1bt1);

    ecc1_mfma<<<E_EDGES / 256, 256, 0, stream>>>(x, e, src, tgt, gcn_w,
        e1_w0, e1_b0, w1bt1, wbt1, cursor, perm, srcp, gwp, msg1);
    gather1<<<N_NODES / 16, 256, 0, stream>>>(msg1, off, x, e1_root, e1_bias, x1);
    ecc2_mfma<<<E_EDGES / 256, 256, 0, stream>>>(x1, e, src, perm,
        e2_w0, e2_b0, w1bt2, wbt2, msg2);
    gather2<<<N_NODES / 8, 256, 0, stream>>>(msg2, off, x1,
        e2_root, e2_bias, gcn_W, xw, out);
    gcn_pool<<<N_NODES / 8, 256, 0, stream>>>(xw, off, srcp, gwp,
        gcn_w, gcn_b, seg, out);
}

// Round 9
// 191.770 us; speedup vs baseline: 1.1662x; 1.1662x over previous
//
#include <hip/hip_runtime.h>
#include <hip/hip_bf16.h>

#define N_NODES 16384
#define E_EDGES 131072
#define F_IN 6
#define S_DIM 4
#define G_GRAPHS 256
#define H_DIM 30
#define C1 32
#define C2 64
#define C3 32

typedef __attribute__((ext_vector_type(2))) _Float16 f16x2;
typedef __attribute__((ext_vector_type(2))) __fp16 fp16v2;
typedef __attribute__((ext_vector_type(8))) _Float16 f16x8;
typedef __attribute__((ext_vector_type(4))) float f32x4;

// f32 -> f16 bits (RNE via v_cvt_f16_f32)
__device__ __forceinline__ unsigned short f2h(float f) {
    union { _Float16 h; unsigned short s; } c; c.h = (_Float16)f; return c.s;
}

// pack two f32 -> packed f16 pair (one v_cvt_pkrtz_f16_f32)
__device__ __forceinline__ unsigned pkh2(float a, float b) {
    union { fp16v2 h; unsigned u; } c; c.h = __builtin_amdgcn_cvt_pkrtz(a, b); return c.u;
}

// duplicate low/high f16 half into both halves (one v_perm_b32)
__device__ __forceinline__ unsigned dup_lo(unsigned v) {
    return __builtin_amdgcn_perm(v, v, 0x01000100u);
}
__device__ __forceinline__ unsigned dup_hi(unsigned v) {
    return __builtin_amdgcn_perm(v, v, 0x03020302u);
}

// packed f16 multiply (one v_pk_mul_f16)
__device__ __forceinline__ unsigned pkmul(unsigned a, unsigned b) {
    union { unsigned u; f16x2 h; } x, y, r;
    x.u = a; y.u = b; r.h = x.h * y.h; return r.u;
}

// pack two f32 -> (bf16 lo, bf16 hi)  [message format, baseline-proven]
__device__ __forceinline__ unsigned pack2(float a, float b) {
    unsigned ua = __float_as_uint(a) + 0x8000u;
    unsigned ub = __float_as_uint(b) + 0x8000u;
    return __builtin_amdgcn_perm(ub, ua, 0x07060302u);
}

// ---------------------------------------------------------------------------
// prep: f16 weight tables + E-parallel degree histogram (deg pre-zeroed by
// memset). grid = E/256 = 512 blocks. [histogram here: 131072 atomics spread
// over 512 blocks is ~free; single-block LDS version was 62 us — round 7]
// ---------------------------------------------------------------------------
__global__ __launch_bounds__(256) void prep(
    const float* __restrict__ wk2, const float* __restrict__ bk2,
    const float* __restrict__ wk1, const float* __restrict__ bk1,
    const float* __restrict__ w1h2, const float* __restrict__ b1h2,
    const float* __restrict__ w1h1, const float* __restrict__ b1h1,
    const int* __restrict__ tgt,
    short* __restrict__ wbt2, short* __restrict__ wbt1,
    short* __restrict__ w1bt2, short* __restrict__ w1bt1,
    int* __restrict__ deg)
{
    const int gtid = blockIdx.x * 256 + threadIdx.x;
    if (gtid < 65536) {
        const int idx = gtid;
        const int j = idx & 7, kq = (idx >> 3) & 3, n = (idx >> 5) & 15;
        const int nt = (idx >> 9) & 3, kc = idx >> 11;
        const int c1 = kq * 8 + j, c2 = nt * 16 + n;
        float v = (kc < 30) ? wk2[kc * 2048 + c1 * 64 + c2]
                            : ((kc == 30) ? bk2[c1 * 64 + c2] : 0.f);
        wbt2[idx] = (short)f2h(v);
    } else if (gtid < 73728) {
        const int i2 = gtid - 65536;
        const int j = i2 & 7, kq = (i2 >> 3) & 3, n = (i2 >> 5) & 15;
        const int nt = (i2 >> 9) & 1, kc = i2 >> 10;
        const int h = kc * 4 + kq, c1 = nt * 16 + n;
        float v = 0.f;
        if (j < 6) {
            if (h < 30) v = wk1[h * 192 + j * 32 + c1];
            else if (h == 30) v = bk1[j * 32 + c1];
        }
        wbt1[i2] = (short)f2h(v);
    } else if (gtid < 74752) {
        // w1bt2[col*32 + k] = B[k][col]: k<30 -> w1[k][col], k==30 -> b1[col]
        const int i3 = gtid - 73728;
        const int col = i3 >> 5, k = i3 & 31;
        float v = 0.f;
        if (col < 30) {
            if (k < 30) v = w1h2[k * 30 + col];
            else if (k == 30) v = b1h2[col];
        }
        w1bt2[i3] = (short)f2h(v);
    } else if (gtid < 75776) {
        const int i4 = gtid - 74752;
        const int col = i4 >> 5, k = i4 & 31;
        float v = 0.f;
        if (col < 30) {
            if (k < 30) v = w1h1[k * 30 + col];
            else if (k == 30) v = b1h1[col];
        }
        w1bt1[i4] = (short)f2h(v);
    }
    atomicAdd(&deg[tgt[gtid]], 1);
}

// single block, 1024 threads, 16 elems/thread exclusive scan over N=16384
__global__ __launch_bounds__(1024) void csr_scan(
    const int* __restrict__ deg, int* __restrict__ off, int* __restrict__ cursor)
{
    __shared__ int s[1024];
    const int t = threadIdx.x;
    const int base = t * 16;
    int loc[16]; int sum = 0;
    #pragma unroll
    for (int i = 0; i < 16; ++i) { loc[i] = sum; sum += deg[base + i]; }
    s[t] = sum;
    __syncthreads();
    int v = sum;
    for (int d = 1; d < 1024; d <<= 1) {
        const int add = (t >= d) ? s[t - d] : 0;
        __syncthreads();
        v += add; s[t] = v;
        __syncthreads();
    }
    const int pre = v - sum;
    #pragma unroll
    for (int i = 0; i < 16; ++i) {
        const int o = pre + loc[i];
        off[base + i] = o; cursor[base + i] = o;
    }
    if (t == 1023) off[N_NODES] = E_EDGES;
}

// ---------------------------------------------------------------------------
// ECC1 + fused CSR permute (round-6-verified).
// ---------------------------------------------------------------------------
__global__ __launch_bounds__(256, 2) void ecc1_mfma(
    const float* __restrict__ x, const float* __restrict__ e,
    const int* __restrict__ src, const int* __restrict__ tgt,
    const float* __restrict__ gcn_w,
    const float* __restrict__ w0, const float* __restrict__ b0,
    const short* __restrict__ w1bt, const short* __restrict__ wbt1,
    int* __restrict__ cursor, int* __restrict__ perm,
    int* __restrict__ srcp, float* __restrict__ gwp,
    unsigned* __restrict__ msg1)
{
    __shared__ unsigned short s_h1b[256 * 40];
    __shared__ unsigned short s_xb[256 * 8];
    __shared__ int s_perm[256];
    __shared__ float s_w0[120], s_b0[30];

    const int t = threadIdx.x;
    const int tile = blockIdx.x * 256;
    for (int i = t; i < 120; i += 256) s_w0[i] = w0[i];
    if (t < 30) s_b0[t] = b0[t];
    __syncthreads();

    // ---- phase A: CSR permute + MLP layer-1 + h0/x staging (f16) ----
    {
        const int eid = tile + t;
        const int sv = src[eid];
        const int p = atomicAdd(&cursor[tgt[eid]], 1);
        s_perm[t] = p;
        perm[eid] = p;
        srcp[p] = sv;
        gwp[p] = gcn_w[eid];

        const float4 ev = *(const float4*)(e + eid * 4);
        float h0[30];
        #pragma unroll
        for (int j = 0; j < 30; ++j) {
            float v = ev.x * s_w0[j] + ev.y * s_w0[30 + j]
                    + ev.z * s_w0[60 + j] + ev.w * s_w0[90 + j] + s_b0[j];
            h0[j] = fmaxf(v, 0.f);
        }
        unsigned hw[16];
        #pragma unroll
        for (int i = 0; i < 15; ++i) hw[i] = pkh2(h0[2 * i], h0[2 * i + 1]);
        hw[15] = pkh2(1.0f, 0.f);
        uint4* hb = (uint4*)&s_h1b[t * 40];
        hb[0] = make_uint4(hw[0], hw[1], hw[2], hw[3]);
        hb[1] = make_uint4(hw[4], hw[5], hw[6], hw[7]);
        hb[2] = make_uint4(hw[8], hw[9], hw[10], hw[11]);
        hb[3] = make_uint4(hw[12], hw[13], hw[14], hw[15]);

        const float2* xp = (const float2*)(x + (size_t)sv * F_IN);
        const float2 a = xp[0], b2 = xp[1], c2 = xp[2];
        *(uint4*)&s_xb[t * 8] =
            make_uint4(pkh2(a.x, a.y), pkh2(b2.x, b2.y), pkh2(c2.x, c2.y), 0u);
    }
    __syncthreads();

    const int wv = t >> 6, lane = t & 63;
    const int n = lane & 15, quad = lane >> 4;
    const int e0 = wv * 64;

    // ---- MLP layer-2 via MFMA: h1 = relu(h0 @ w1 + b1), in-place (f16) ----
    {
        const f16x8 wf0 = *(const f16x8*)(w1bt + n * 32 + quad * 8);
        const f16x8 wf1 = *(const f16x8*)(w1bt + (16 + n) * 32 + quad * 8);
        #pragma unroll
        for (int m = 0; m < 4; ++m) {
            const f16x8 a0 = *(const f16x8*)&s_h1b[(e0 + m * 16 + n) * 40 + quad * 8];
            f32x4 c0 = {0.f, 0.f, 0.f, 0.f}, c1 = {0.f, 0.f, 0.f, 0.f};
            c0 = __builtin_amdgcn_mfma_f32_16x16x32_f16(a0, wf0, c0, 0, 0, 0);
            c1 = __builtin_amdgcn_mfma_f32_16x16x32_f16(a0, wf1, c1, 0, 0, 0);
            #pragma unroll
            for (int r = 0; r < 4; ++r) {
                const int row = e0 + m * 16 + quad * 4 + r;
                s_h1b[row * 40 + n] = f2h(fmaxf(c0[r], 0.f));
                s_h1b[row * 40 + 16 + n] = (n == 14) ? (unsigned short)0x3C00
                                                     : f2h(fmaxf(c1[r], 0.f));
            }
        }
    }
    __syncthreads();

    // ---- main MFMA: A = dup(h) * packed-x ----
    unsigned xpk[4][3];
    #pragma unroll
    for (int m = 0; m < 4; ++m) {
        const uint4 xv = *(const uint4*)&s_xb[(e0 + m * 16 + n) * 8];
        xpk[m][0] = xv.x; xpk[m][1] = xv.y; xpk[m][2] = xv.z;
    }

    f32x4 acc[4][2];
    #pragma unroll
    for (int m = 0; m < 4; ++m) {
        acc[m][0] = (f32x4){0.f, 0.f, 0.f, 0.f};
        acc[m][1] = (f32x4){0.f, 0.f, 0.f, 0.f};
    }

    #pragma unroll
    for (int kc = 0; kc < 8; ++kc) {
        f16x8 bfr[2];
        #pragma unroll
        for (int nt = 0; nt < 2; ++nt)
            bfr[nt] = *(const f16x8*)(wbt1 + (((kc * 2 + nt) * 16 + n) << 5) + quad * 8);
        #pragma unroll
        for (int m = 0; m < 4; ++m) {
            const unsigned hv = s_h1b[(e0 + m * 16 + n) * 40 + kc * 4 + quad];
            const unsigned hh = dup_lo(hv);
            union { unsigned u[4]; f16x8 v; } af;
            af.u[0] = pkmul(hh, xpk[m][0]);
            af.u[1] = pkmul(hh, xpk[m][1]);
            af.u[2] = pkmul(hh, xpk[m][2]);
            af.u[3] = 0u;
            acc[m][0] = __builtin_amdgcn_mfma_f32_16x16x32_f16(af.v, bfr[0], acc[m][0], 0, 0, 0);
            acc[m][1] = __builtin_amdgcn_mfma_f32_16x16x32_f16(af.v, bfr[1], acc[m][1], 0, 0, 0);
        }
    }

    #pragma unroll
    for (int m = 0; m < 4; ++m)
        #pragma unroll
        for (int r = 0; r < 4; ++r) {
            const int p = s_perm[e0 + m * 16 + quad * 4 + r];
            msg1[p * 16 + n] = pack2(acc[m][0][r], acc[m][1][r]);
        }
}

// gather msg1 (SEQUENTIAL, permuted layout) + node update 1 -> x1
__global__ __launch_bounds__(256) void gather1(
    const unsigned* __restrict__ msg1, const int* __restrict__ off,
    const float* __restrict__ x,
    const float* __restrict__ root, const float* __restrict__ bias,
    float* __restrict__ x1)
{
    __shared__ float s_root[192];
    __shared__ float s_b[32];
    const int t = threadIdx.x;
    if (t < 192) s_root[t] = root[t];
    if (t < 32) s_b[t] = bias[t];
    __syncthreads();
    const int v = blockIdx.x * 16 + (t >> 4);
    const int n = t & 15;
    const int o0 = off[v], o1 = off[v + 1];
    float sa = 0.f, sb = 0.f;
    for (int j = o0; j < o1; ++j) {
        const unsigned u = msg1[j * 16 + n];
        sa += __uint_as_float(u << 16);
        sb += __uint_as_float(u & 0xFFFF0000u);
    }
    const float* xr = x + (size_t)v * F_IN;
    float ra = s_b[n], rb = s_b[16 + n];
    #pragma unroll
    for (int f = 0; f < 6; ++f) {
        const float xv = xr[f];
        ra += xv * s_root[f * 32 + n];
        rb += xv * s_root[f * 32 + 16 + n];
    }
    x1[v * 32 + n] = fmaxf(sa + ra, 0.f);
    x1[v * 32 + 16 + n] = fmaxf(sb + rb, 0.f);
}

// ---------------------------------------------------------------------------
// ECC2 (round-6-verified).
// ---------------------------------------------------------------------------
__global__ __launch_bounds__(256, 2) void ecc2_mfma(
    const float* __restrict__ x1, const float* __restrict__ e,
    const int* __restrict__ src, const int* __restrict__ perm,
    const float* __restrict__ w0, const float* __restrict__ b0,
    const short* __restrict__ w1bt, const short* __restrict__ wbt2,
    unsigned* __restrict__ msg2)
{
    __shared__ unsigned short s_h1b[256 * 40];
    __shared__ unsigned short s_x1b[256 * 40];
    __shared__ int s_perm[256];
    __shared__ float s_w0[120], s_b0[30];

    const int t = threadIdx.x;
    const int tile = blockIdx.x * 256;
    for (int i = t; i < 120; i += 256) s_w0[i] = w0[i];
    if (t < 30) s_b0[t] = b0[t];
    __syncthreads();

    // ---- phase A ----
    {
        const int eid = tile + t;
        s_perm[t] = perm[eid];
        const float4 ev = *(const float4*)(e + eid * 4);
        float h0[30];
        #pragma unroll
        for (int j = 0; j < 30; ++j) {
            float v = ev.x * s_w0[j] + ev.y * s_w0[30 + j]
                    + ev.z * s_w0[60 + j] + ev.w * s_w0[90 + j] + s_b0[j];
            h0[j] = fmaxf(v, 0.f);
        }
        unsigned hw[16];
        #pragma unroll
        for (int i = 0; i < 15; ++i) hw[i] = pkh2(h0[2 * i], h0[2 * i + 1]);
        hw[15] = pkh2(1.0f, 0.f);
        uint4* hb = (uint4*)&s_h1b[t * 40];
        hb[0] = make_uint4(hw[0], hw[1], hw[2], hw[3]);
        hb[1] = make_uint4(hw[4], hw[5], hw[6], hw[7]);
        hb[2] = make_uint4(hw[8], hw[9], hw[10], hw[11]);
        hb[3] = make_uint4(hw[12], hw[13], hw[14], hw[15]);

        const float* xp = x1 + (size_t)src[eid] * C1;
        uint4* xb = (uint4*)&s_x1b[t * 40];
        #pragma unroll
        for (int q = 0; q < 4; ++q) {
            const float4 v0 = *(const float4*)(xp + q * 8);
            const float4 v1 = *(const float4*)(xp + q * 8 + 4);
            xb[q] = make_uint4(pkh2(v0.x, v0.y), pkh2(v0.z, v0.w),
                               pkh2(v1.x, v1.y), pkh2(v1.z, v1.w));
        }
    }
    __syncthreads();

    const int wv = t >> 6, lane = t & 63;
    const int n = lane & 15, quad = lane >> 4;
    const int e0 = wv * 64;

    // ---- MLP layer-2 via MFMA, in-place (f16) ----
    {
        const f16x8 wf0 = *(const f16x8*)(w1bt + n * 32 + quad * 8);
        const f16x8 wf1 = *(const f16x8*)(w1bt + (16 + n) * 32 + quad * 8);
        #pragma unroll
        for (int m = 0; m < 4; ++m) {
            const f16x8 a0 = *(const f16x8*)&s_h1b[(e0 + m * 16 + n) * 40 + quad * 8];
            f32x4 c0 = {0.f, 0.f, 0.f, 0.f}, c1 = {0.f, 0.f, 0.f, 0.f};
            c0 = __builtin_amdgcn_mfma_f32_16x16x32_f16(a0, wf0, c0, 0, 0, 0);
            c1 = __builtin_amdgcn_mfma_f32_16x16x32_f16(a0, wf1, c1, 0, 0, 0);
            #pragma unroll
            for (int r = 0; r < 4; ++r) {
                const int row = e0 + m * 16 + quad * 4 + r;
                s_h1b[row * 40 + n] = f2h(fmaxf(c0[r], 0.f));
                s_h1b[row * 40 + 16 + n] = (n == 14) ? (unsigned short)0x3C00
                                                     : f2h(fmaxf(c1[r], 0.f));
            }
        }
    }
    __syncthreads();

    // ---- main MFMA: A = dup(h) * packed-x1 ----
    unsigned xpk[4][4];
    #pragma unroll
    for (int m = 0; m < 4; ++m) {
        const uint4 xv = *(const uint4*)&s_x1b[(e0 + m * 16 + n) * 40 + quad * 8];
        xpk[m][0] = xv.x; xpk[m][1] = xv.y; xpk[m][2] = xv.z; xpk[m][3] = xv.w;
    }

    f32x4 acc[4][4];
    #pragma unroll
    for (int m = 0; m < 4; ++m)
        #pragma unroll
        for (int nt = 0; nt < 4; ++nt) acc[m][nt] = (f32x4){0.f, 0.f, 0.f, 0.f};

    #pragma unroll
    for (int kb = 0; kb < 4; ++kb) {
        unsigned hqa[4][4];
        #pragma unroll
        for (int m = 0; m < 4; ++m)
            *(uint4*)&hqa[m][0] = *(const uint4*)&s_h1b[(e0 + m * 16 + n) * 40 + kb * 8];
        #pragma unroll
        for (int k8 = 0; k8 < 8; ++k8) {
            const int kc = kb * 8 + k8;
            f16x8 bfr[4];
            #pragma unroll
            for (int nt = 0; nt < 4; ++nt)
                bfr[nt] = *(const f16x8*)(wbt2 + (((kc * 4 + nt) * 16 + n) << 5) + quad * 8);
            #pragma unroll
            for (int m = 0; m < 4; ++m) {
                const unsigned hu = hqa[m][k8 >> 1];
                const unsigned hh = (k8 & 1) ? dup_hi(hu) : dup_lo(hu);
                union { unsigned u[4]; f16x8 v; } af;
                af.u[0] = pkmul(hh, xpk[m][0]);
                af.u[1] = pkmul(hh, xpk[m][1]);
                af.u[2] = pkmul(hh, xpk[m][2]);
                af.u[3] = pkmul(hh, xpk[m][3]);
                #pragma unroll
                for (int nt = 0; nt < 4; ++nt)
                    acc[m][nt] = __builtin_amdgcn_mfma_f32_16x16x32_f16(af.v, bfr[nt], acc[m][nt], 0, 0, 0);
            }
        }
    }

    #pragma unroll
    for (int m = 0; m < 4; ++m)
        #pragma unroll
        for (int r = 0; r < 4; ++r) {
            const int p = s_perm[e0 + m * 16 + quad * 4 + r];
            uint2 val;
            val.x = pack2(acc[m][0][r], acc[m][1][r]);
            val.y = pack2(acc[m][2][r], acc[m][3][r]);
            *(uint2*)&msg2[p * 32 + n * 2] = val;
        }
}

// gather msg2 (sequential) + node update 2 + xw = x2 @ gcn_W -> xw
// Also zeroes `out` (blocks 0..31) so no separate memset dispatch is needed.
__global__ __launch_bounds__(256) void gather2(
    const unsigned* __restrict__ msg2, const int* __restrict__ off,
    const float* __restrict__ x1,
    const float* __restrict__ root, const float* __restrict__ bias,
    const float* __restrict__ W, float* __restrict__ xw,
    float* __restrict__ out)
{
    __shared__ float s_root[2048], s_W[2048], s_b[64];
    __shared__ float s_x2[8][68];
    __shared__ float s_x1v[256];
    const int t = threadIdx.x;
    if (blockIdx.x < 32) out[blockIdx.x * 256 + t] = 0.f;   // G*C3 = 8192
    for (int i = t; i < 2048; i += 256) { s_root[i] = root[i]; s_W[i] = W[i]; }
    if (t < 64) s_b[t] = bias[t];
    s_x1v[t] = x1[blockIdx.x * 256 + t];
    __syncthreads();

    const int lv = t >> 5;
    const int v = blockIdx.x * 8 + lv;
    const int j5 = t & 31;
    const int n = j5 >> 1, p = j5 & 1;
    const int ca = p * 32 + n, cb = p * 32 + 16 + n;
    const int o0 = off[v], o1 = off[v + 1];
    float sa = 0.f, sb = 0.f;
    for (int j = o0; j < o1; ++j) {
        const unsigned u = msg2[j * 32 + j5];
        sa += __uint_as_float(u << 16);
        sb += __uint_as_float(u & 0xFFFF0000u);
    }
    float ra = s_b[ca], rb = s_b[cb];
    #pragma unroll 8
    for (int k = 0; k < 32; ++k) {
        const float xv = s_x1v[lv * 32 + k];
        ra += xv * s_root[k * 64 + ca];
        rb += xv * s_root[k * 64 + cb];
    }
    s_x2[lv][ca] = fmaxf(sa + ra, 0.f);
    s_x2[lv][cb] = fmaxf(sb + rb, 0.f);
    __syncthreads();

    float av = 0.f;
    #pragma unroll 8
    for (int k = 0; k < 64; ++k) av += s_x2[lv][k] * s_W[k * 32 + j5];
    xw[v * 32 + j5] = av;
}

// GCN gather + relu + global pool. seg is sorted: when all 8 nodes of the
// block share one graph (common case), LDS-reduce and emit ONE atomicAdd
// per channel instead of 8.
__global__ __launch_bounds__(256) void gcn_pool(
    const float* __restrict__ xw, const int* __restrict__ off,
    const int* __restrict__ srcp, const float* __restrict__ gwp,
    const float* __restrict__ gw, const float* __restrict__ gb,
    const int* __restrict__ seg, float* __restrict__ out)
{
    __shared__ float s_gb[32];
    __shared__ float s_vals[8][32];
    __shared__ int s_seg[8];
    const int t = threadIdx.x;
    const int lv = t >> 5;
    const int c = t & 31;
    const int v = blockIdx.x * 8 + lv;
    if (t < 32) s_gb[t] = gb[t];
    if (c == 0) s_seg[lv] = seg[v];
    __syncthreads();
    const int o0 = off[v], o1 = off[v + 1];
    float s = gw[E_EDGES + v] * xw[v * 32 + c];   // self loop
    for (int j = o0; j < o1; ++j)
        s += gwp[j] * xw[srcp[j] * 32 + c];
    const float val = fmaxf(s + s_gb[c], 0.f);
    if (s_seg[0] == s_seg[7]) {          // block-uniform graph (seg sorted)
        s_vals[lv][c] = val;
        __syncthreads();
        if (lv == 0) {
            float acc = s_vals[0][c] + s_vals[1][c] + s_vals[2][c] + s_vals[3][c]
                      + s_vals[4][c] + s_vals[5][c] + s_vals[6][c] + s_vals[7][c];
            atomicAdd(&out[s_seg[0] * 32 + c], acc);
        }
    } else {
        atomicAdd(&out[s_seg[lv] * 32 + c], val);
    }
}

extern "C" void kernel_launch(void* const* d_in, const int* in_sizes, int n_in,
                              void* d_out, int out_size, void* d_ws, size_t ws_size,
                              hipStream_t stream)
{
    const float* x       = (const float*)d_in[0];
    const float* e       = (const float*)d_in[1];
    const int*   src     = (const int*)d_in[2];
    const int*   tgt     = (const int*)d_in[3];
    const int*   seg     = (const int*)d_in[4];
    const float* gcn_w   = (const float*)d_in[7];
    const float* e1_w0   = (const float*)d_in[8];
    const float* e1_b0   = (const float*)d_in[9];
    const float* e1_w1   = (const float*)d_in[10];
    const float* e1_b1   = (const float*)d_in[11];
    const float* e1_wk   = (const float*)d_in[12];
    const float* e1_bk   = (const float*)d_in[13];
    const float* e1_root = (const float*)d_in[14];
    const float* e1_bias = (const float*)d_in[15];
    const float* e2_w0   = (const float*)d_in[16];
    const float* e2_b0   = (const float*)d_in[17];
    const float* e2_w1   = (const float*)d_in[18];
    const float* e2_b1   = (const float*)d_in[19];
    const float* e2_wk   = (const float*)d_in[20];
    const float* e2_bk   = (const float*)d_in[21];
    const float* e2_root = (const float*)d_in[22];
    const float* e2_bias = (const float*)d_in[23];
    const float* gcn_W   = (const float*)d_in[24];
    const float* gcn_b   = (const float*)d_in[25];
    float* out = (float*)d_out;

    float*    ws    = (float*)d_ws;
    float*    x1    = ws;                                   // [N,32]
    float*    xw    = x1 + (size_t)N_NODES * 32;            // [N,32]
    unsigned* msg1  = (unsigned*)(xw + (size_t)N_NODES * 32);   // E*16 u32
    unsigned* msg2  = msg1 + (size_t)E_EDGES * 16;          // E*32 u32
    short*    wbt2  = (short*)(msg2 + (size_t)E_EDGES * 32);// 65536 f16
    short*    wbt1  = wbt2 + 65536;                         // 8192 f16
    short*    w1bt2 = wbt1 + 8192;                          // 1024 f16
    short*    w1bt1 = w1bt2 + 1024;                         // 1024 f16
    int*      deg   = (int*)(w1bt1 + 1024);                 // N
    int*      off   = deg + N_NODES;                        // N+1 (+pad)
    int*      cursor= off + N_NODES + 16;                   // N
    int*      perm  = cursor + N_NODES;                     // E
    int*      srcp  = perm + E_EDGES;                       // E
    float*    gwp   = (float*)(srcp + E_EDGES);             // E

    hipMemsetAsync(deg, 0, N_NODES * sizeof(int), stream);

    prep<<<E_EDGES / 256, 256, 0, stream>>>(e2_wk, e2_bk, e1_wk, e1_bk,
        e2_w1, e2_b1, e1_w1, e1_b1, tgt, wbt2, wbt1, w1bt2, w1bt1, deg);
    csr_scan<<<1, 1024, 0, stream>>>(deg, off, cursor);

    ecc1_mfma<<<E_EDGES / 256, 256, 0, stream>>>(x, e, src, tgt, gcn_w,
        e1_w0, e1_b0, w1bt1, wbt1, cursor, perm, srcp, gwp, msg1);
    gather1<<<N_NODES / 16, 256, 0, stream>>>(msg1, off, x, e1_root, e1_bias, x1);
    ecc2_mfma<<<E_EDGES / 256, 256, 0, stream>>>(x1, e, src, perm,
        e2_w0, e2_b0, w1bt2, wbt2, msg2);
    gather2<<<N_NODES / 8, 256, 0, stream>>>(msg2, off, x1,
        e2_root, e2_bias, gcn_W, xw, out);
    gcn_pool<<<N_NODES / 8, 256, 0, stream>>>(xw, off, srcp, gwp,
        gcn_w, gcn_b, seg, out);
}

// Round 10
// 191.147 us; speedup vs baseline: 1.1700x; 1.0033x over previous
//
#include <hip/hip_runtime.h>
#include <hip/hip_bf16.h>

#define N_NODES 16384
#define E_EDGES 131072
#define F_IN 6
#define S_DIM 4
#define G_GRAPHS 256
#define H_DIM 30
#define C1 32
#define C2 64
#define C3 32

typedef __attribute__((ext_vector_type(2))) _Float16 f16x2;
typedef __attribute__((ext_vector_type(2))) __fp16 fp16v2;
typedef __attribute__((ext_vector_type(8))) _Float16 f16x8;
typedef __attribute__((ext_vector_type(4))) float f32x4;

// f32 -> f16 bits (RNE via v_cvt_f16_f32)
__device__ __forceinline__ unsigned short f2h(float f) {
    union { _Float16 h; unsigned short s; } c; c.h = (_Float16)f; return c.s;
}

// pack two f32 -> packed f16 pair (one v_cvt_pkrtz_f16_f32)
__device__ __forceinline__ unsigned pkh2(float a, float b) {
    union { fp16v2 h; unsigned u; } c; c.h = __builtin_amdgcn_cvt_pkrtz(a, b); return c.u;
}

// duplicate low/high f16 half into both halves (one v_perm_b32)
__device__ __forceinline__ unsigned dup_lo(unsigned v) {
    return __builtin_amdgcn_perm(v, v, 0x01000100u);
}
__device__ __forceinline__ unsigned dup_hi(unsigned v) {
    return __builtin_amdgcn_perm(v, v, 0x03020302u);
}

// packed f16 multiply (one v_pk_mul_f16)
__device__ __forceinline__ unsigned pkmul(unsigned a, unsigned b) {
    union { unsigned u; f16x2 h; } x, y, r;
    x.u = a; y.u = b; r.h = x.h * y.h; return r.u;
}

// pack two f32 -> (bf16 lo, bf16 hi)  [message format, baseline-proven]
__device__ __forceinline__ unsigned pack2(float a, float b) {
    unsigned ua = __float_as_uint(a) + 0x8000u;
    unsigned ub = __float_as_uint(b) + 0x8000u;
    return __builtin_amdgcn_perm(ub, ua, 0x07060302u);
}

// ---------------------------------------------------------------------------
// prep: f16 weight tables + E-parallel degree histogram (deg pre-zeroed by
// memset). grid = E/256 = 512 blocks.
// ---------------------------------------------------------------------------
__global__ __launch_bounds__(256) void prep(
    const float* __restrict__ wk2, const float* __restrict__ bk2,
    const float* __restrict__ wk1, const float* __restrict__ bk1,
    const float* __restrict__ w1h2, const float* __restrict__ b1h2,
    const float* __restrict__ w1h1, const float* __restrict__ b1h1,
    const int* __restrict__ tgt,
    short* __restrict__ wbt2, short* __restrict__ wbt1,
    short* __restrict__ w1bt2, short* __restrict__ w1bt1,
    int* __restrict__ deg)
{
    const int gtid = blockIdx.x * 256 + threadIdx.x;
    if (gtid < 65536) {
        const int idx = gtid;
        const int j = idx & 7, kq = (idx >> 3) & 3, n = (idx >> 5) & 15;
        const int nt = (idx >> 9) & 3, kc = idx >> 11;
        const int c1 = kq * 8 + j, c2 = nt * 16 + n;
        float v = (kc < 30) ? wk2[kc * 2048 + c1 * 64 + c2]
                            : ((kc == 30) ? bk2[c1 * 64 + c2] : 0.f);
        wbt2[idx] = (short)f2h(v);
    } else if (gtid < 73728) {
        const int i2 = gtid - 65536;
        const int j = i2 & 7, kq = (i2 >> 3) & 3, n = (i2 >> 5) & 15;
        const int nt = (i2 >> 9) & 1, kc = i2 >> 10;
        const int h = kc * 4 + kq, c1 = nt * 16 + n;
        float v = 0.f;
        if (j < 6) {
            if (h < 30) v = wk1[h * 192 + j * 32 + c1];
            else if (h == 30) v = bk1[j * 32 + c1];
        }
        wbt1[i2] = (short)f2h(v);
    } else if (gtid < 74752) {
        // w1bt2[col*32 + k] = B[k][col]: k<30 -> w1[k][col], k==30 -> b1[col]
        const int i3 = gtid - 73728;
        const int col = i3 >> 5, k = i3 & 31;
        float v = 0.f;
        if (col < 30) {
            if (k < 30) v = w1h2[k * 30 + col];
            else if (k == 30) v = b1h2[col];
        }
        w1bt2[i3] = (short)f2h(v);
    } else if (gtid < 75776) {
        const int i4 = gtid - 74752;
        const int col = i4 >> 5, k = i4 & 31;
        float v = 0.f;
        if (col < 30) {
            if (k < 30) v = w1h1[k * 30 + col];
            else if (k == 30) v = b1h1[col];
        }
        w1bt1[i4] = (short)f2h(v);
    }
    atomicAdd(&deg[tgt[gtid]], 1);
}

// single block, 1024 threads, 16 elems/thread exclusive scan over N=16384
__global__ __launch_bounds__(1024) void csr_scan(
    const int* __restrict__ deg, int* __restrict__ off, int* __restrict__ cursor)
{
    __shared__ int s[1024];
    const int t = threadIdx.x;
    const int base = t * 16;
    int loc[16]; int sum = 0;
    #pragma unroll
    for (int i = 0; i < 16; ++i) { loc[i] = sum; sum += deg[base + i]; }
    s[t] = sum;
    __syncthreads();
    int v = sum;
    for (int d = 1; d < 1024; d <<= 1) {
        const int add = (t >= d) ? s[t - d] : 0;
        __syncthreads();
        v += add; s[t] = v;
        __syncthreads();
    }
    const int pre = v - sum;
    #pragma unroll
    for (int i = 0; i < 16; ++i) {
        const int o = pre + loc[i];
        off[base + i] = o; cursor[base + i] = o;
    }
    if (t == 1023) off[N_NODES] = E_EDGES;
}

// ---------------------------------------------------------------------------
// ECC1 + fused CSR permute. ONE WAVE per 64-edge tile (grid = E/64 = 2048):
// round 9 showed 256-thread/256-edge blocks cap the grid at 2 blocks/CU ->
// 16% occupancy, latency-bound (MfmaUtil 14%). 1-wave blocks pack ~16/CU.
// __syncthreads() in a 1-wave block is a free compiler fence (TBAA, round 1).
// ---------------------------------------------------------------------------
__global__ __launch_bounds__(64) void ecc1_mfma(
    const float* __restrict__ x, const float* __restrict__ e,
    const int* __restrict__ src, const int* __restrict__ tgt,
    const float* __restrict__ gcn_w,
    const float* __restrict__ w0, const float* __restrict__ b0,
    const short* __restrict__ w1bt, const short* __restrict__ wbt1,
    int* __restrict__ cursor, int* __restrict__ perm,
    int* __restrict__ srcp, float* __restrict__ gwp,
    unsigned* __restrict__ msg1)
{
    __shared__ unsigned short s_h1b[64 * 40];
    __shared__ unsigned short s_xb[64 * 8];
    __shared__ int s_perm[64];
    __shared__ float s_w0[120], s_b0[30];

    const int t = threadIdx.x;
    const int tile = blockIdx.x * 64;
    for (int i = t; i < 120; i += 64) s_w0[i] = w0[i];
    if (t < 30) s_b0[t] = b0[t];
    __syncthreads();

    // ---- phase A: CSR permute + MLP layer-1 + h0/x staging (f16) ----
    {
        const int eid = tile + t;
        const int sv = src[eid];
        const int p = atomicAdd(&cursor[tgt[eid]], 1);
        s_perm[t] = p;
        perm[eid] = p;
        srcp[p] = sv;
        gwp[p] = gcn_w[eid];

        const float4 ev = *(const float4*)(e + eid * 4);
        float h0[30];
        #pragma unroll
        for (int j = 0; j < 30; ++j) {
            float v = ev.x * s_w0[j] + ev.y * s_w0[30 + j]
                    + ev.z * s_w0[60 + j] + ev.w * s_w0[90 + j] + s_b0[j];
            h0[j] = fmaxf(v, 0.f);
        }
        unsigned hw[16];
        #pragma unroll
        for (int i = 0; i < 15; ++i) hw[i] = pkh2(h0[2 * i], h0[2 * i + 1]);
        hw[15] = pkh2(1.0f, 0.f);
        uint4* hb = (uint4*)&s_h1b[t * 40];
        hb[0] = make_uint4(hw[0], hw[1], hw[2], hw[3]);
        hb[1] = make_uint4(hw[4], hw[5], hw[6], hw[7]);
        hb[2] = make_uint4(hw[8], hw[9], hw[10], hw[11]);
        hb[3] = make_uint4(hw[12], hw[13], hw[14], hw[15]);

        const float2* xp = (const float2*)(x + (size_t)sv * F_IN);
        const float2 a = xp[0], b2 = xp[1], c2 = xp[2];
        *(uint4*)&s_xb[t * 8] =
            make_uint4(pkh2(a.x, a.y), pkh2(b2.x, b2.y), pkh2(c2.x, c2.y), 0u);
    }
    __syncthreads();

    const int n = t & 15, quad = t >> 4;

    // ---- MLP layer-2 via MFMA: h1 = relu(h0 @ w1 + b1), in-place (f16) ----
    {
        const f16x8 wf0 = *(const f16x8*)(w1bt + n * 32 + quad * 8);
        const f16x8 wf1 = *(const f16x8*)(w1bt + (16 + n) * 32 + quad * 8);
        #pragma unroll
        for (int m = 0; m < 4; ++m) {
            const f16x8 a0 = *(const f16x8*)&s_h1b[(m * 16 + n) * 40 + quad * 8];
            f32x4 c0 = {0.f, 0.f, 0.f, 0.f}, c1 = {0.f, 0.f, 0.f, 0.f};
            c0 = __builtin_amdgcn_mfma_f32_16x16x32_f16(a0, wf0, c0, 0, 0, 0);
            c1 = __builtin_amdgcn_mfma_f32_16x16x32_f16(a0, wf1, c1, 0, 0, 0);
            #pragma unroll
            for (int r = 0; r < 4; ++r) {
                const int row = m * 16 + quad * 4 + r;
                s_h1b[row * 40 + n] = f2h(fmaxf(c0[r], 0.f));
                s_h1b[row * 40 + 16 + n] = (n == 14) ? (unsigned short)0x3C00
                                                     : f2h(fmaxf(c1[r], 0.f));
            }
        }
    }
    __syncthreads();

    // ---- main MFMA: A = dup(h) * packed-x ----
    unsigned xpk[4][3];
    #pragma unroll
    for (int m = 0; m < 4; ++m) {
        const uint4 xv = *(const uint4*)&s_xb[(m * 16 + n) * 8];
        xpk[m][0] = xv.x; xpk[m][1] = xv.y; xpk[m][2] = xv.z;
    }

    f32x4 acc[4][2];
    #pragma unroll
    for (int m = 0; m < 4; ++m) {
        acc[m][0] = (f32x4){0.f, 0.f, 0.f, 0.f};
        acc[m][1] = (f32x4){0.f, 0.f, 0.f, 0.f};
    }

    #pragma unroll
    for (int kc = 0; kc < 8; ++kc) {
        f16x8 bfr[2];
        #pragma unroll
        for (int nt = 0; nt < 2; ++nt)
            bfr[nt] = *(const f16x8*)(wbt1 + (((kc * 2 + nt) * 16 + n) << 5) + quad * 8);
        #pragma unroll
        for (int m = 0; m < 4; ++m) {
            const unsigned hv = s_h1b[(m * 16 + n) * 40 + kc * 4 + quad];
            const unsigned hh = dup_lo(hv);
            union { unsigned u[4]; f16x8 v; } af;
            af.u[0] = pkmul(hh, xpk[m][0]);
            af.u[1] = pkmul(hh, xpk[m][1]);
            af.u[2] = pkmul(hh, xpk[m][2]);
            af.u[3] = 0u;
            acc[m][0] = __builtin_amdgcn_mfma_f32_16x16x32_f16(af.v, bfr[0], acc[m][0], 0, 0, 0);
            acc[m][1] = __builtin_amdgcn_mfma_f32_16x16x32_f16(af.v, bfr[1], acc[m][1], 0, 0, 0);
        }
    }

    #pragma unroll
    for (int m = 0; m < 4; ++m)
        #pragma unroll
        for (int r = 0; r < 4; ++r) {
            const int p = s_perm[m * 16 + quad * 4 + r];
            msg1[p * 16 + n] = pack2(acc[m][0][r], acc[m][1][r]);
        }
}

// gather msg1 (SEQUENTIAL, permuted layout) + node update 1 -> x1
__global__ __launch_bounds__(256) void gather1(
    const unsigned* __restrict__ msg1, const int* __restrict__ off,
    const float* __restrict__ x,
    const float* __restrict__ root, const float* __restrict__ bias,
    float* __restrict__ x1)
{
    __shared__ float s_root[192];
    __shared__ float s_b[32];
    const int t = threadIdx.x;
    if (t < 192) s_root[t] = root[t];
    if (t < 32) s_b[t] = bias[t];
    __syncthreads();
    const int v = blockIdx.x * 16 + (t >> 4);
    const int n = t & 15;
    const int o0 = off[v], o1 = off[v + 1];
    float sa = 0.f, sb = 0.f;
    for (int j = o0; j < o1; ++j) {
        const unsigned u = msg1[j * 16 + n];
        sa += __uint_as_float(u << 16);
        sb += __uint_as_float(u & 0xFFFF0000u);
    }
    const float* xr = x + (size_t)v * F_IN;
    float ra = s_b[n], rb = s_b[16 + n];
    #pragma unroll
    for (int f = 0; f < 6; ++f) {
        const float xv = xr[f];
        ra += xv * s_root[f * 32 + n];
        rb += xv * s_root[f * 32 + 16 + n];
    }
    x1[v * 32 + n] = fmaxf(sa + ra, 0.f);
    x1[v * 32 + 16 + n] = fmaxf(sb + rb, 0.f);
}

// ---------------------------------------------------------------------------
// ECC2: one wave per 64-edge tile (grid = E/64 = 2048). See ecc1 comment.
// ---------------------------------------------------------------------------
__global__ __launch_bounds__(64) void ecc2_mfma(
    const float* __restrict__ x1, const float* __restrict__ e,
    const int* __restrict__ src, const int* __restrict__ perm,
    const float* __restrict__ w0, const float* __restrict__ b0,
    const short* __restrict__ w1bt, const short* __restrict__ wbt2,
    unsigned* __restrict__ msg2)
{
    __shared__ unsigned short s_h1b[64 * 40];
    __shared__ unsigned short s_x1b[64 * 40];
    __shared__ int s_perm[64];
    __shared__ float s_w0[120], s_b0[30];

    const int t = threadIdx.x;
    const int tile = blockIdx.x * 64;
    for (int i = t; i < 120; i += 64) s_w0[i] = w0[i];
    if (t < 30) s_b0[t] = b0[t];
    __syncthreads();

    // ---- phase A ----
    {
        const int eid = tile + t;
        s_perm[t] = perm[eid];
        const float4 ev = *(const float4*)(e + eid * 4);
        float h0[30];
        #pragma unroll
        for (int j = 0; j < 30; ++j) {
            float v = ev.x * s_w0[j] + ev.y * s_w0[30 + j]
                    + ev.z * s_w0[60 + j] + ev.w * s_w0[90 + j] + s_b0[j];
            h0[j] = fmaxf(v, 0.f);
        }
        unsigned hw[16];
        #pragma unroll
        for (int i = 0; i < 15; ++i) hw[i] = pkh2(h0[2 * i], h0[2 * i + 1]);
        hw[15] = pkh2(1.0f, 0.f);
        uint4* hb = (uint4*)&s_h1b[t * 40];
        hb[0] = make_uint4(hw[0], hw[1], hw[2], hw[3]);
        hb[1] = make_uint4(hw[4], hw[5], hw[6], hw[7]);
        hb[2] = make_uint4(hw[8], hw[9], hw[10], hw[11]);
        hb[3] = make_uint4(hw[12], hw[13], hw[14], hw[15]);

        const float* xp = x1 + (size_t)src[eid] * C1;
        uint4* xb = (uint4*)&s_x1b[t * 40];
        #pragma unroll
        for (int q = 0; q < 4; ++q) {
            const float4 v0 = *(const float4*)(xp + q * 8);
            const float4 v1 = *(const float4*)(xp + q * 8 + 4);
            xb[q] = make_uint4(pkh2(v0.x, v0.y), pkh2(v0.z, v0.w),
                               pkh2(v1.x, v1.y), pkh2(v1.z, v1.w));
        }
    }
    __syncthreads();

    const int n = t & 15, quad = t >> 4;

    // ---- MLP layer-2 via MFMA, in-place (f16) ----
    {
        const f16x8 wf0 = *(const f16x8*)(w1bt + n * 32 + quad * 8);
        const f16x8 wf1 = *(const f16x8*)(w1bt + (16 + n) * 32 + quad * 8);
        #pragma unroll
        for (int m = 0; m < 4; ++m) {
            const f16x8 a0 = *(const f16x8*)&s_h1b[(m * 16 + n) * 40 + quad * 8];
            f32x4 c0 = {0.f, 0.f, 0.f, 0.f}, c1 = {0.f, 0.f, 0.f, 0.f};
            c0 = __builtin_amdgcn_mfma_f32_16x16x32_f16(a0, wf0, c0, 0, 0, 0);
            c1 = __builtin_amdgcn_mfma_f32_16x16x32_f16(a0, wf1, c1, 0, 0, 0);
            #pragma unroll
            for (int r = 0; r < 4; ++r) {
                const int row = m * 16 + quad * 4 + r;
                s_h1b[row * 40 + n] = f2h(fmaxf(c0[r], 0.f));
                s_h1b[row * 40 + 16 + n] = (n == 14) ? (unsigned short)0x3C00
                                                     : f2h(fmaxf(c1[r], 0.f));
            }
        }
    }
    __syncthreads();

    // ---- main MFMA: A = dup(h) * packed-x1 ----
    unsigned xpk[4][4];
    #pragma unroll
    for (int m = 0; m < 4; ++m) {
        const uint4 xv = *(const uint4*)&s_x1b[(m * 16 + n) * 40 + quad * 8];
        xpk[m][0] = xv.x; xpk[m][1] = xv.y; xpk[m][2] = xv.z; xpk[m][3] = xv.w;
    }

    f32x4 acc[4][4];
    #pragma unroll
    for (int m = 0; m < 4; ++m)
        #pragma unroll
        for (int nt = 0; nt < 4; ++nt) acc[m][nt] = (f32x4){0.f, 0.f, 0.f, 0.f};

    #pragma unroll
    for (int kb = 0; kb < 4; ++kb) {
        unsigned hqa[4][4];
        #pragma unroll
        for (int m = 0; m < 4; ++m)
            *(uint4*)&hqa[m][0] = *(const uint4*)&s_h1b[(m * 16 + n) * 40 + kb * 8];
        #pragma unroll
        for (int k8 = 0; k8 < 8; ++k8) {
            const int kc = kb * 8 + k8;
            f16x8 bfr[4];
            #pragma unroll
            for (int nt = 0; nt < 4; ++nt)
                bfr[nt] = *(const f16x8*)(wbt2 + (((kc * 4 + nt) * 16 + n) << 5) + quad * 8);
            #pragma unroll
            for (int m = 0; m < 4; ++m) {
                const unsigned hu = hqa[m][k8 >> 1];
                const unsigned hh = (k8 & 1) ? dup_hi(hu) : dup_lo(hu);
                union { unsigned u[4]; f16x8 v; } af;
                af.u[0] = pkmul(hh, xpk[m][0]);
                af.u[1] = pkmul(hh, xpk[m][1]);
                af.u[2] = pkmul(hh, xpk[m][2]);
                af.u[3] = pkmul(hh, xpk[m][3]);
                #pragma unroll
                for (int nt = 0; nt < 4; ++nt)
                    acc[m][nt] = __builtin_amdgcn_mfma_f32_16x16x32_f16(af.v, bfr[nt], acc[m][nt], 0, 0, 0);
            }
        }
    }

    #pragma unroll
    for (int m = 0; m < 4; ++m)
        #pragma unroll
        for (int r = 0; r < 4; ++r) {
            const int p = s_perm[m * 16 + quad * 4 + r];
            uint2 val;
            val.x = pack2(acc[m][0][r], acc[m][1][r]);
            val.y = pack2(acc[m][2][r], acc[m][3][r]);
            *(uint2*)&msg2[p * 32 + n * 2] = val;
        }
}

// gather msg2 (sequential) + node update 2 + xw = x2 @ gcn_W -> xw
// Also zeroes `out` (blocks 0..31) so no separate memset dispatch is needed.
__global__ __launch_bounds__(256) void gather2(
    const unsigned* __restrict__ msg2, const int* __restrict__ off,
    const float* __restrict__ x1,
    const float* __restrict__ root, const float* __restrict__ bias,
    const float* __restrict__ W, float* __restrict__ xw,
    float* __restrict__ out)
{
    __shared__ float s_root[2048], s_W[2048], s_b[64];
    __shared__ float s_x2[8][68];
    __shared__ float s_x1v[256];
    const int t = threadIdx.x;
    if (blockIdx.x < 32) out[blockIdx.x * 256 + t] = 0.f;   // G*C3 = 8192
    for (int i = t; i < 2048; i += 256) { s_root[i] = root[i]; s_W[i] = W[i]; }
    if (t < 64) s_b[t] = bias[t];
    s_x1v[t] = x1[blockIdx.x * 256 + t];
    __syncthreads();

    const int lv = t >> 5;
    const int v = blockIdx.x * 8 + lv;
    const int j5 = t & 31;
    const int n = j5 >> 1, p = j5 & 1;
    const int ca = p * 32 + n, cb = p * 32 + 16 + n;
    const int o0 = off[v], o1 = off[v + 1];
    float sa = 0.f, sb = 0.f;
    for (int j = o0; j < o1; ++j) {
        const unsigned u = msg2[j * 32 + j5];
        sa += __uint_as_float(u << 16);
        sb += __uint_as_float(u & 0xFFFF0000u);
    }
    float ra = s_b[ca], rb = s_b[cb];
    #pragma unroll 8
    for (int k = 0; k < 32; ++k) {
        const float xv = s_x1v[lv * 32 + k];
        ra += xv * s_root[k * 64 + ca];
        rb += xv * s_root[k * 64 + cb];
    }
    s_x2[lv][ca] = fmaxf(sa + ra, 0.f);
    s_x2[lv][cb] = fmaxf(sb + rb, 0.f);
    __syncthreads();

    float av = 0.f;
    #pragma unroll 8
    for (int k = 0; k < 64; ++k) av += s_x2[lv][k] * s_W[k * 32 + j5];
    xw[v * 32 + j5] = av;
}

// GCN gather + relu + global pool. seg is sorted: when all 8 nodes of the
// block share one graph (common case), LDS-reduce and emit ONE atomicAdd
// per channel instead of 8.
__global__ __launch_bounds__(256) void gcn_pool(
    const float* __restrict__ xw, const int* __restrict__ off,
    const int* __restrict__ srcp, const float* __restrict__ gwp,
    const float* __restrict__ gw, const float* __restrict__ gb,
    const int* __restrict__ seg, float* __restrict__ out)
{
    __shared__ float s_gb[32];
    __shared__ float s_vals[8][32];
    __shared__ int s_seg[8];
    const int t = threadIdx.x;
    const int lv = t >> 5;
    const int c = t & 31;
    const int v = blockIdx.x * 8 + lv;
    if (t < 32) s_gb[t] = gb[t];
    if (c == 0) s_seg[lv] = seg[v];
    __syncthreads();
    const int o0 = off[v], o1 = off[v + 1];
    float s = gw[E_EDGES + v] * xw[v * 32 + c];   // self loop
    for (int j = o0; j < o1; ++j)
        s += gwp[j] * xw[srcp[j] * 32 + c];
    const float val = fmaxf(s + s_gb[c], 0.f);
    if (s_seg[0] == s_seg[7]) {          // block-uniform graph (seg sorted)
        s_vals[lv][c] = val;
        __syncthreads();
        if (lv == 0) {
            float acc = s_vals[0][c] + s_vals[1][c] + s_vals[2][c] + s_vals[3][c]
                      + s_vals[4][c] + s_vals[5][c] + s_vals[6][c] + s_vals[7][c];
            atomicAdd(&out[s_seg[0] * 32 + c], acc);
        }
    } else {
        atomicAdd(&out[s_seg[lv] * 32 + c], val);
    }
}

extern "C" void kernel_launch(void* const* d_in, const int* in_sizes, int n_in,
                              void* d_out, int out_size, void* d_ws, size_t ws_size,
                              hipStream_t stream)
{
    const float* x       = (const float*)d_in[0];
    const float* e       = (const float*)d_in[1];
    const int*   src     = (const int*)d_in[2];
    const int*   tgt     = (const int*)d_in[3];
    const int*   seg     = (const int*)d_in[4];
    const float* gcn_w   = (const float*)d_in[7];
    const float* e1_w0   = (const float*)d_in[8];
    const float* e1_b0   = (const float*)d_in[9];
    const float* e1_w1   = (const float*)d_in[10];
    const float* e1_b1   = (const float*)d_in[11];
    const float* e1_wk   = (const float*)d_in[12];
    const float* e1_bk   = (const float*)d_in[13];
    const float* e1_root = (const float*)d_in[14];
    const float* e1_bias = (const float*)d_in[15];
    const float* e2_w0   = (const float*)d_in[16];
    const float* e2_b0   = (const float*)d_in[17];
    const float* e2_w1   = (const float*)d_in[18];
    const float* e2_b1   = (const float*)d_in[19];
    const float* e2_wk   = (const float*)d_in[20];
    const float* e2_bk   = (const float*)d_in[21];
    const float* e2_root = (const float*)d_in[22];
    const float* e2_bias = (const float*)d_in[23];
    const float* gcn_W   = (const float*)d_in[24];
    const float* gcn_b   = (const float*)d_in[25];
    float* out = (float*)d_out;

    float*    ws    = (float*)d_ws;
    float*    x1    = ws;                                   // [N,32]
    float*    xw    = x1 + (size_t)N_NODES * 32;            // [N,32]
    unsigned* msg1  = (unsigned*)(xw + (size_t)N_NODES * 32);   // E*16 u32
    unsigned* msg2  = msg1 + (size_t)E_EDGES * 16;          // E*32 u32
    short*    wbt2  = (short*)(msg2 + (size_t)E_EDGES * 32);// 65536 f16
    short*    wbt1  = wbt2 + 65536;                         // 8192 f16
    short*    w1bt2 = wbt1 + 8192;                          // 1024 f16
    short*    w1bt1 = w1bt2 + 1024;                         // 1024 f16
    int*      deg   = (int*)(w1bt1 + 1024);                 // N
    int*      off   = deg + N_NODES;                        // N+1 (+pad)
    int*      cursor= off + N_NODES + 16;                   // N
    int*      perm  = cursor + N_NODES;                     // E
    int*      srcp  = perm + E_EDGES;                       // E
    float*    gwp   = (float*)(srcp + E_EDGES);             // E

    hipMemsetAsync(deg, 0, N_NODES * sizeof(int), stream);

    prep<<<E_EDGES / 256, 256, 0, stream>>>(e2_wk, e2_bk, e1_wk, e1_bk,
        e2_w1, e2_b1, e1_w1, e1_b1, tgt, wbt2, wbt1, w1bt2, w1bt1, deg);
    csr_scan<<<1, 1024, 0, stream>>>(deg, off, cursor);

    ecc1_mfma<<<E_EDGES / 64, 64, 0, stream>>>(x, e, src, tgt, gcn_w,
        e1_w0, e1_b0, w1bt1, wbt1, cursor, perm, srcp, gwp, msg1);
    gather1<<<N_NODES / 16, 256, 0, stream>>>(msg1, off, x, e1_root, e1_bias, x1);
    ecc2_mfma<<<E_EDGES / 64, 64, 0, stream>>>(x1, e, src, perm,
        e2_w0, e2_b0, w1bt2, wbt2, msg2);
    gather2<<<N_NODES / 8, 256, 0, stream>>>(msg2, off, x1,
        e2_root, e2_bias, gcn_W, xw, out);
    gcn_pool<<<N_NODES / 8, 256, 0, stream>>>(xw, off, srcp, gwp,
        gcn_w, gcn_b, seg, out);
}

// Round 11
// 190.225 us; speedup vs baseline: 1.1757x; 1.0048x over previous
//
#include <hip/hip_runtime.h>
#include <hip/hip_bf16.h>

#define N_NODES 16384
#define E_EDGES 131072
#define F_IN 6
#define S_DIM 4
#define G_GRAPHS 256
#define H_DIM 30
#define C1 32
#define C2 64
#define C3 32

typedef __attribute__((ext_vector_type(2))) _Float16 f16x2;
typedef __attribute__((ext_vector_type(2))) __fp16 fp16v2;
typedef __attribute__((ext_vector_type(8))) _Float16 f16x8;
typedef __attribute__((ext_vector_type(4))) float f32x4;

// f32 -> f16 bits (RNE via v_cvt_f16_f32)
__device__ __forceinline__ unsigned short f2h(float f) {
    union { _Float16 h; unsigned short s; } c; c.h = (_Float16)f; return c.s;
}

// pack two f32 -> packed f16 pair (one v_cvt_pkrtz_f16_f32)
__device__ __forceinline__ unsigned pkh2(float a, float b) {
    union { fp16v2 h; unsigned u; } c; c.h = __builtin_amdgcn_cvt_pkrtz(a, b); return c.u;
}

// duplicate low/high f16 half into both halves (one v_perm_b32)
__device__ __forceinline__ unsigned dup_lo(unsigned v) {
    return __builtin_amdgcn_perm(v, v, 0x01000100u);
}
__device__ __forceinline__ unsigned dup_hi(unsigned v) {
    return __builtin_amdgcn_perm(v, v, 0x03020302u);
}

// packed f16 multiply (one v_pk_mul_f16)
__device__ __forceinline__ unsigned pkmul(unsigned a, unsigned b) {
    union { unsigned u; f16x2 h; } x, y, r;
    x.u = a; y.u = b; r.h = x.h * y.h; return r.u;
}

// pack two f32 -> (bf16 lo, bf16 hi)  [message format, baseline-proven]
__device__ __forceinline__ unsigned pack2(float a, float b) {
    unsigned ua = __float_as_uint(a) + 0x8000u;
    unsigned ub = __float_as_uint(b) + 0x8000u;
    return __builtin_amdgcn_perm(ub, ua, 0x07060302u);
}

// ---------------------------------------------------------------------------
// prep: f16 weight tables + E-parallel degree histogram (deg pre-zeroed by
// memset). grid = E/256 = 512 blocks.
// ---------------------------------------------------------------------------
__global__ __launch_bounds__(256) void prep(
    const float* __restrict__ wk2, const float* __restrict__ bk2,
    const float* __restrict__ wk1, const float* __restrict__ bk1,
    const float* __restrict__ w1h2, const float* __restrict__ b1h2,
    const float* __restrict__ w1h1, const float* __restrict__ b1h1,
    const int* __restrict__ tgt,
    short* __restrict__ wbt2, short* __restrict__ wbt1,
    short* __restrict__ w1bt2, short* __restrict__ w1bt1,
    int* __restrict__ deg)
{
    const int gtid = blockIdx.x * 256 + threadIdx.x;
    if (gtid < 65536) {
        const int idx = gtid;
        const int j = idx & 7, kq = (idx >> 3) & 3, n = (idx >> 5) & 15;
        const int nt = (idx >> 9) & 3, kc = idx >> 11;
        const int c1 = kq * 8 + j, c2 = nt * 16 + n;
        float v = (kc < 30) ? wk2[kc * 2048 + c1 * 64 + c2]
                            : ((kc == 30) ? bk2[c1 * 64 + c2] : 0.f);
        wbt2[idx] = (short)f2h(v);
    } else if (gtid < 73728) {
        const int i2 = gtid - 65536;
        const int j = i2 & 7, kq = (i2 >> 3) & 3, n = (i2 >> 5) & 15;
        const int nt = (i2 >> 9) & 1, kc = i2 >> 10;
        const int h = kc * 4 + kq, c1 = nt * 16 + n;
        float v = 0.f;
        if (j < 6) {
            if (h < 30) v = wk1[h * 192 + j * 32 + c1];
            else if (h == 30) v = bk1[j * 32 + c1];
        }
        wbt1[i2] = (short)f2h(v);
    } else if (gtid < 74752) {
        // w1bt2[col*32 + k] = B[k][col]: k<30 -> w1[k][col], k==30 -> b1[col]
        const int i3 = gtid - 73728;
        const int col = i3 >> 5, k = i3 & 31;
        float v = 0.f;
        if (col < 30) {
            if (k < 30) v = w1h2[k * 30 + col];
            else if (k == 30) v = b1h2[col];
        }
        w1bt2[i3] = (short)f2h(v);
    } else if (gtid < 75776) {
        const int i4 = gtid - 74752;
        const int col = i4 >> 5, k = i4 & 31;
        float v = 0.f;
        if (col < 30) {
            if (k < 30) v = w1h1[k * 30 + col];
            else if (k == 30) v = b1h1[col];
        }
        w1bt1[i4] = (short)f2h(v);
    }
    atomicAdd(&deg[tgt[gtid]], 1);
}

// single block, 1024 threads, 16 elems/thread exclusive scan over N=16384
__global__ __launch_bounds__(1024) void csr_scan(
    const int* __restrict__ deg, int* __restrict__ off, int* __restrict__ cursor)
{
    __shared__ int s[1024];
    const int t = threadIdx.x;
    const int base = t * 16;
    int loc[16]; int sum = 0;
    #pragma unroll
    for (int i = 0; i < 16; ++i) { loc[i] = sum; sum += deg[base + i]; }
    s[t] = sum;
    __syncthreads();
    int v = sum;
    for (int d = 1; d < 1024; d <<= 1) {
        const int add = (t >= d) ? s[t - d] : 0;
        __syncthreads();
        v += add; s[t] = v;
        __syncthreads();
    }
    const int pre = v - sum;
    #pragma unroll
    for (int i = 0; i < 16; ++i) {
        const int o = pre + loc[i];
        off[base + i] = o; cursor[base + i] = o;
    }
    if (t == 1023) off[N_NODES] = E_EDGES;
}

// ---------------------------------------------------------------------------
// ECC1 + fused CSR permute. wbt1 (16 KB) staged once into LDS: it exceeds
// nothing, but B-reads become LDS-latency instead of L2. 3 blocks/CU by LDS.
// ---------------------------------------------------------------------------
__global__ __launch_bounds__(256, 3) void ecc1_mfma(
    const float* __restrict__ x, const float* __restrict__ e,
    const int* __restrict__ src, const int* __restrict__ tgt,
    const float* __restrict__ gcn_w,
    const float* __restrict__ w0, const float* __restrict__ b0,
    const short* __restrict__ w1bt, const short* __restrict__ wbt1,
    int* __restrict__ cursor, int* __restrict__ perm,
    int* __restrict__ srcp, float* __restrict__ gwp,
    unsigned* __restrict__ msg1)
{
    __shared__ unsigned short s_h1b[256 * 40];
    __shared__ unsigned short s_xb[256 * 8];
    __shared__ unsigned short s_wbt[8192];   // full wbt1: 16 KB
    __shared__ int s_perm[256];
    __shared__ float s_w0[120], s_b0[30];

    const int t = threadIdx.x;
    const int tile = blockIdx.x * 256;
    // stage wbt1 -> LDS (coalesced, 64 B/thread); overlaps with phase A setup
    {
        const short* gsrc = wbt1 + t * 32;
        uint4* dst = (uint4*)&s_wbt[t * 32];
        dst[0] = *(const uint4*)(gsrc);
        dst[1] = *(const uint4*)(gsrc + 8);
        dst[2] = *(const uint4*)(gsrc + 16);
        dst[3] = *(const uint4*)(gsrc + 24);
    }
    for (int i = t; i < 120; i += 256) s_w0[i] = w0[i];
    if (t < 30) s_b0[t] = b0[t];
    __syncthreads();

    // ---- phase A: CSR permute + MLP layer-1 + h0/x staging (f16) ----
    {
        const int eid = tile + t;
        const int sv = src[eid];
        const int p = atomicAdd(&cursor[tgt[eid]], 1);
        s_perm[t] = p;
        perm[eid] = p;
        srcp[p] = sv;
        gwp[p] = gcn_w[eid];

        const float4 ev = *(const float4*)(e + eid * 4);
        float h0[30];
        #pragma unroll
        for (int j = 0; j < 30; ++j) {
            float v = ev.x * s_w0[j] + ev.y * s_w0[30 + j]
                    + ev.z * s_w0[60 + j] + ev.w * s_w0[90 + j] + s_b0[j];
            h0[j] = fmaxf(v, 0.f);
        }
        unsigned hw[16];
        #pragma unroll
        for (int i = 0; i < 15; ++i) hw[i] = pkh2(h0[2 * i], h0[2 * i + 1]);
        hw[15] = pkh2(1.0f, 0.f);
        uint4* hb = (uint4*)&s_h1b[t * 40];
        hb[0] = make_uint4(hw[0], hw[1], hw[2], hw[3]);
        hb[1] = make_uint4(hw[4], hw[5], hw[6], hw[7]);
        hb[2] = make_uint4(hw[8], hw[9], hw[10], hw[11]);
        hb[3] = make_uint4(hw[12], hw[13], hw[14], hw[15]);

        const float2* xp = (const float2*)(x + (size_t)sv * F_IN);
        const float2 a = xp[0], b2 = xp[1], c2 = xp[2];
        *(uint4*)&s_xb[t * 8] =
            make_uint4(pkh2(a.x, a.y), pkh2(b2.x, b2.y), pkh2(c2.x, c2.y), 0u);
    }
    __syncthreads();

    const int wv = t >> 6, lane = t & 63;
    const int n = lane & 15, quad = lane >> 4;
    const int e0 = wv * 64;

    // ---- MLP layer-2 via MFMA: h1 = relu(h0 @ w1 + b1), in-place (f16) ----
    {
        const f16x8 wf0 = *(const f16x8*)(w1bt + n * 32 + quad * 8);
        const f16x8 wf1 = *(const f16x8*)(w1bt + (16 + n) * 32 + quad * 8);
        #pragma unroll
        for (int m = 0; m < 4; ++m) {
            const f16x8 a0 = *(const f16x8*)&s_h1b[(e0 + m * 16 + n) * 40 + quad * 8];
            f32x4 c0 = {0.f, 0.f, 0.f, 0.f}, c1 = {0.f, 0.f, 0.f, 0.f};
            c0 = __builtin_amdgcn_mfma_f32_16x16x32_f16(a0, wf0, c0, 0, 0, 0);
            c1 = __builtin_amdgcn_mfma_f32_16x16x32_f16(a0, wf1, c1, 0, 0, 0);
            #pragma unroll
            for (int r = 0; r < 4; ++r) {
                const int row = e0 + m * 16 + quad * 4 + r;
                s_h1b[row * 40 + n] = f2h(fmaxf(c0[r], 0.f));
                s_h1b[row * 40 + 16 + n] = (n == 14) ? (unsigned short)0x3C00
                                                     : f2h(fmaxf(c1[r], 0.f));
            }
        }
    }
    __syncthreads();

    // ---- main MFMA: A = dup(h) * packed-x, B from LDS ----
    unsigned xpk[4][3];
    #pragma unroll
    for (int m = 0; m < 4; ++m) {
        const uint4 xv = *(const uint4*)&s_xb[(e0 + m * 16 + n) * 8];
        xpk[m][0] = xv.x; xpk[m][1] = xv.y; xpk[m][2] = xv.z;
    }

    f32x4 acc[4][2];
    #pragma unroll
    for (int m = 0; m < 4; ++m) {
        acc[m][0] = (f32x4){0.f, 0.f, 0.f, 0.f};
        acc[m][1] = (f32x4){0.f, 0.f, 0.f, 0.f};
    }

    #pragma unroll
    for (int kc = 0; kc < 8; ++kc) {
        f16x8 bfr[2];
        #pragma unroll
        for (int nt = 0; nt < 2; ++nt)
            bfr[nt] = *(const f16x8*)&s_wbt[(((kc * 2 + nt) * 16 + n) << 5) + quad * 8];
        #pragma unroll
        for (int m = 0; m < 4; ++m) {
            const unsigned hv = s_h1b[(e0 + m * 16 + n) * 40 + kc * 4 + quad];
            const unsigned hh = dup_lo(hv);
            union { unsigned u[4]; f16x8 v; } af;
            af.u[0] = pkmul(hh, xpk[m][0]);
            af.u[1] = pkmul(hh, xpk[m][1]);
            af.u[2] = pkmul(hh, xpk[m][2]);
            af.u[3] = 0u;
            acc[m][0] = __builtin_amdgcn_mfma_f32_16x16x32_f16(af.v, bfr[0], acc[m][0], 0, 0, 0);
            acc[m][1] = __builtin_amdgcn_mfma_f32_16x16x32_f16(af.v, bfr[1], acc[m][1], 0, 0, 0);
        }
    }

    #pragma unroll
    for (int m = 0; m < 4; ++m)
        #pragma unroll
        for (int r = 0; r < 4; ++r) {
            const int p = s_perm[e0 + m * 16 + quad * 4 + r];
            msg1[p * 16 + n] = pack2(acc[m][0][r], acc[m][1][r]);
        }
}

// gather msg1 (SEQUENTIAL, permuted layout) + node update 1 -> x1
__global__ __launch_bounds__(256) void gather1(
    const unsigned* __restrict__ msg1, const int* __restrict__ off,
    const float* __restrict__ x,
    const float* __restrict__ root, const float* __restrict__ bias,
    float* __restrict__ x1)
{
    __shared__ float s_root[192];
    __shared__ float s_b[32];
    const int t = threadIdx.x;
    if (t < 192) s_root[t] = root[t];
    if (t < 32) s_b[t] = bias[t];
    __syncthreads();
    const int v = blockIdx.x * 16 + (t >> 4);
    const int n = t & 15;
    const int o0 = off[v], o1 = off[v + 1];
    float sa = 0.f, sb = 0.f;
    for (int j = o0; j < o1; ++j) {
        const unsigned u = msg1[j * 16 + n];
        sa += __uint_as_float(u << 16);
        sb += __uint_as_float(u & 0xFFFF0000u);
    }
    const float* xr = x + (size_t)v * F_IN;
    float ra = s_b[n], rb = s_b[16 + n];
    #pragma unroll
    for (int f = 0; f < 6; ++f) {
        const float xv = xr[f];
        ra += xv * s_root[f * 32 + n];
        rb += xv * s_root[f * 32 + 16 + n];
    }
    x1[v * 32 + n] = fmaxf(sa + ra, 0.f);
    x1[v * 32 + 16 + n] = fmaxf(sb + rb, 0.f);
}

// ---------------------------------------------------------------------------
// ECC2: wbt2 is 128 KB — misses the 32 KB L1, so per-lane B-loads were 128
// L2 round-trips per wave (round-10 PMC: MfmaUtil 14%, all pipes idle).
// Fix: phase loop stages 8 x 16 KB slices into LDS cooperatively (coalesced),
// inner loop reads B from LDS. h/x fragments preloaded to registers so
// phases only touch s_wbt. L2 table traffic: 512 KB -> 128 KB per block.
// ---------------------------------------------------------------------------
__global__ __launch_bounds__(256, 2) void ecc2_mfma(
    const float* __restrict__ x1, const float* __restrict__ e,
    const int* __restrict__ src, const int* __restrict__ perm,
    const float* __restrict__ w0, const float* __restrict__ b0,
    const short* __restrict__ w1bt, const short* __restrict__ wbt2,
    unsigned* __restrict__ msg2)
{
    __shared__ unsigned short s_h1b[256 * 40];
    __shared__ unsigned short s_x1b[256 * 40];
    __shared__ unsigned short s_wbt[8192];   // 16 KB slice: 4 kc x 4 nt x 16 x 32
    __shared__ int s_perm[256];
    __shared__ float s_w0[120], s_b0[30];

    const int t = threadIdx.x;
    const int tile = blockIdx.x * 256;
    for (int i = t; i < 120; i += 256) s_w0[i] = w0[i];
    if (t < 30) s_b0[t] = b0[t];
    __syncthreads();

    // ---- phase A ----
    {
        const int eid = tile + t;
        s_perm[t] = perm[eid];
        const float4 ev = *(const float4*)(e + eid * 4);
        float h0[30];
        #pragma unroll
        for (int j = 0; j < 30; ++j) {
            float v = ev.x * s_w0[j] + ev.y * s_w0[30 + j]
                    + ev.z * s_w0[60 + j] + ev.w * s_w0[90 + j] + s_b0[j];
            h0[j] = fmaxf(v, 0.f);
        }
        unsigned hw[16];
        #pragma unroll
        for (int i = 0; i < 15; ++i) hw[i] = pkh2(h0[2 * i], h0[2 * i + 1]);
        hw[15] = pkh2(1.0f, 0.f);
        uint4* hb = (uint4*)&s_h1b[t * 40];
        hb[0] = make_uint4(hw[0], hw[1], hw[2], hw[3]);
        hb[1] = make_uint4(hw[4], hw[5], hw[6], hw[7]);
        hb[2] = make_uint4(hw[8], hw[9], hw[10], hw[11]);
        hb[3] = make_uint4(hw[12], hw[13], hw[14], hw[15]);

        const float* xp = x1 + (size_t)src[eid] * C1;
        uint4* xb = (uint4*)&s_x1b[t * 40];
        #pragma unroll
        for (int q = 0; q < 4; ++q) {
            const float4 v0 = *(const float4*)(xp + q * 8);
            const float4 v1 = *(const float4*)(xp + q * 8 + 4);
            xb[q] = make_uint4(pkh2(v0.x, v0.y), pkh2(v0.z, v0.w),
                               pkh2(v1.x, v1.y), pkh2(v1.z, v1.w));
        }
    }
    __syncthreads();

    const int wv = t >> 6, lane = t & 63;
    const int n = lane & 15, quad = lane >> 4;
    const int e0 = wv * 64;

    // ---- MLP layer-2 via MFMA, in-place (f16) ----
    {
        const f16x8 wf0 = *(const f16x8*)(w1bt + n * 32 + quad * 8);
        const f16x8 wf1 = *(const f16x8*)(w1bt + (16 + n) * 32 + quad * 8);
        #pragma unroll
        for (int m = 0; m < 4; ++m) {
            const f16x8 a0 = *(const f16x8*)&s_h1b[(e0 + m * 16 + n) * 40 + quad * 8];
            f32x4 c0 = {0.f, 0.f, 0.f, 0.f}, c1 = {0.f, 0.f, 0.f, 0.f};
            c0 = __builtin_amdgcn_mfma_f32_16x16x32_f16(a0, wf0, c0, 0, 0, 0);
            c1 = __builtin_amdgcn_mfma_f32_16x16x32_f16(a0, wf1, c1, 0, 0, 0);
            #pragma unroll
            for (int r = 0; r < 4; ++r) {
                const int row = e0 + m * 16 + quad * 4 + r;
                s_h1b[row * 40 + n] = f2h(fmaxf(c0[r], 0.f));
                s_h1b[row * 40 + 16 + n] = (n == 14) ? (unsigned short)0x3C00
                                                     : f2h(fmaxf(c1[r], 0.f));
            }
        }
    }
    __syncthreads();

    // ---- preload h (32 kc) and x fragments into registers ----
    unsigned hreg[4][16];
    #pragma unroll
    for (int m = 0; m < 4; ++m) {
        const unsigned short* row = &s_h1b[(e0 + m * 16 + n) * 40];
        #pragma unroll
        for (int q = 0; q < 4; ++q)
            *(uint4*)&hreg[m][q * 4] = *(const uint4*)(row + q * 8);
    }
    unsigned xpk[4][4];
    #pragma unroll
    for (int m = 0; m < 4; ++m) {
        const uint4 xv = *(const uint4*)&s_x1b[(e0 + m * 16 + n) * 40 + quad * 8];
        xpk[m][0] = xv.x; xpk[m][1] = xv.y; xpk[m][2] = xv.z; xpk[m][3] = xv.w;
    }

    f32x4 acc[4][4];
    #pragma unroll
    for (int m = 0; m < 4; ++m)
        #pragma unroll
        for (int nt = 0; nt < 4; ++nt) acc[m][nt] = (f32x4){0.f, 0.f, 0.f, 0.f};

    // ---- 8 phases: stage 16 KB of wbt2 -> LDS, then 4 kc x 16 MFMA/wave ----
    #pragma unroll
    for (int ph = 0; ph < 8; ++ph) {
        __syncthreads();   // previous slice's readers are done
        {
            const short* gsrc = wbt2 + ph * 8192 + t * 32;
            uint4* dst = (uint4*)&s_wbt[t * 32];
            dst[0] = *(const uint4*)(gsrc);
            dst[1] = *(const uint4*)(gsrc + 8);
            dst[2] = *(const uint4*)(gsrc + 16);
            dst[3] = *(const uint4*)(gsrc + 24);
        }
        __syncthreads();   // slice visible
        #pragma unroll
        for (int k4 = 0; k4 < 4; ++k4) {
            const int kc = ph * 4 + k4;
            f16x8 bfr[4];
            #pragma unroll
            for (int nt = 0; nt < 4; ++nt)
                bfr[nt] = *(const f16x8*)&s_wbt[((k4 * 4 + nt) * 16 + n) * 32 + quad * 8];
            #pragma unroll
            for (int m = 0; m < 4; ++m) {
                const unsigned hu = hreg[m][kc >> 1];
                const unsigned hh = (kc & 1) ? dup_hi(hu) : dup_lo(hu);
                union { unsigned u[4]; f16x8 v; } af;
                af.u[0] = pkmul(hh, xpk[m][0]);
                af.u[1] = pkmul(hh, xpk[m][1]);
                af.u[2] = pkmul(hh, xpk[m][2]);
                af.u[3] = pkmul(hh, xpk[m][3]);
                #pragma unroll
                for (int nt = 0; nt < 4; ++nt)
                    acc[m][nt] = __builtin_amdgcn_mfma_f32_16x16x32_f16(af.v, bfr[nt], acc[m][nt], 0, 0, 0);
            }
        }
    }

    #pragma unroll
    for (int m = 0; m < 4; ++m)
        #pragma unroll
        for (int r = 0; r < 4; ++r) {
            const int p = s_perm[e0 + m * 16 + quad * 4 + r];
            uint2 val;
            val.x = pack2(acc[m][0][r], acc[m][1][r]);
            val.y = pack2(acc[m][2][r], acc[m][3][r]);
            *(uint2*)&msg2[p * 32 + n * 2] = val;
        }
}

// gather msg2 (sequential) + node update 2 + xw = x2 @ gcn_W -> xw
// Also zeroes `out` (blocks 0..31) so no separate memset dispatch is needed.
__global__ __launch_bounds__(256) void gather2(
    const unsigned* __restrict__ msg2, const int* __restrict__ off,
    const float* __restrict__ x1,
    const float* __restrict__ root, const float* __restrict__ bias,
    const float* __restrict__ W, float* __restrict__ xw,
    float* __restrict__ out)
{
    __shared__ float s_root[2048], s_W[2048], s_b[64];
    __shared__ float s_x2[8][68];
    __shared__ float s_x1v[256];
    const int t = threadIdx.x;
    if (blockIdx.x < 32) out[blockIdx.x * 256 + t] = 0.f;   // G*C3 = 8192
    for (int i = t; i < 2048; i += 256) { s_root[i] = root[i]; s_W[i] = W[i]; }
    if (t < 64) s_b[t] = bias[t];
    s_x1v[t] = x1[blockIdx.x * 256 + t];
    __syncthreads();

    const int lv = t >> 5;
    const int v = blockIdx.x * 8 + lv;
    const int j5 = t & 31;
    const int n = j5 >> 1, p = j5 & 1;
    const int ca = p * 32 + n, cb = p * 32 + 16 + n;
    const int o0 = off[v], o1 = off[v + 1];
    float sa = 0.f, sb = 0.f;
    for (int j = o0; j < o1; ++j) {
        const unsigned u = msg2[j * 32 + j5];
        sa += __uint_as_float(u << 16);
        sb += __uint_as_float(u & 0xFFFF0000u);
    }
    float ra = s_b[ca], rb = s_b[cb];
    #pragma unroll 8
    for (int k = 0; k < 32; ++k) {
        const float xv = s_x1v[lv * 32 + k];
        ra += xv * s_root[k * 64 + ca];
        rb += xv * s_root[k * 64 + cb];
    }
    s_x2[lv][ca] = fmaxf(sa + ra, 0.f);
    s_x2[lv][cb] = fmaxf(sb + rb, 0.f);
    __syncthreads();

    float av = 0.f;
    #pragma unroll 8
    for (int k = 0; k < 64; ++k) av += s_x2[lv][k] * s_W[k * 32 + j5];
    xw[v * 32 + j5] = av;
}

// GCN gather + relu + global pool. seg is sorted: when all 8 nodes of the
// block share one graph (common case), LDS-reduce and emit ONE atomicAdd
// per channel instead of 8.
__global__ __launch_bounds__(256) void gcn_pool(
    const float* __restrict__ xw, const int* __restrict__ off,
    const int* __restrict__ srcp, const float* __restrict__ gwp,
    const float* __restrict__ gw, const float* __restrict__ gb,
    const int* __restrict__ seg, float* __restrict__ out)
{
    __shared__ float s_gb[32];
    __shared__ float s_vals[8][32];
    __shared__ int s_seg[8];
    const int t = threadIdx.x;
    const int lv = t >> 5;
    const int c = t & 31;
    const int v = blockIdx.x * 8 + lv;
    if (t < 32) s_gb[t] = gb[t];
    if (c == 0) s_seg[lv] = seg[v];
    __syncthreads();
    const int o0 = off[v], o1 = off[v + 1];
    float s = gw[E_EDGES + v] * xw[v * 32 + c];   // self loop
    for (int j = o0; j < o1; ++j)
        s += gwp[j] * xw[srcp[j] * 32 + c];
    const float val = fmaxf(s + s_gb[c], 0.f);
    if (s_seg[0] == s_seg[7]) {          // block-uniform graph (seg sorted)
        s_vals[lv][c] = val;
        __syncthreads();
        if (lv == 0) {
            float acc = s_vals[0][c] + s_vals[1][c] + s_vals[2][c] + s_vals[3][c]
                      + s_vals[4][c] + s_vals[5][c] + s_vals[6][c] + s_vals[7][c];
            atomicAdd(&out[s_seg[0] * 32 + c], acc);
        }
    } else {
        atomicAdd(&out[s_seg[lv] * 32 + c], val);
    }
}

extern "C" void kernel_launch(void* const* d_in, const int* in_sizes, int n_in,
                              void* d_out, int out_size, void* d_ws, size_t ws_size,
                              hipStream_t stream)
{
    const float* x       = (const float*)d_in[0];
    const float* e       = (const float*)d_in[1];
    const int*   src     = (const int*)d_in[2];
    const int*   tgt     = (const int*)d_in[3];
    const int*   seg     = (const int*)d_in[4];
    const float* gcn_w   = (const float*)d_in[7];
    const float* e1_w0   = (const float*)d_in[8];
    const float* e1_b0   = (const float*)d_in[9];
    const float* e1_w1   = (const float*)d_in[10];
    const float* e1_b1   = (const float*)d_in[11];
    const float* e1_wk   = (const float*)d_in[12];
    const float* e1_bk   = (const float*)d_in[13];
    const float* e1_root = (const float*)d_in[14];
    const float* e1_bias = (const float*)d_in[15];
    const float* e2_w0   = (const float*)d_in[16];
    const float* e2_b0   = (const float*)d_in[17];
    const float* e2_w1   = (const float*)d_in[18];
    const float* e2_b1   = (const float*)d_in[19];
    const float* e2_wk   = (const float*)d_in[20];
    const float* e2_bk   = (const float*)d_in[21];
    const float* e2_root = (const float*)d_in[22];
    const float* e2_bias = (const float*)d_in[23];
    const float* gcn_W   = (const float*)d_in[24];
    const float* gcn_b   = (const float*)d_in[25];
    float* out = (float*)d_out;

    float*    ws    = (float*)d_ws;
    float*    x1    = ws;                                   // [N,32]
    float*    xw    = x1 + (size_t)N_NODES * 32;            // [N,32]
    unsigned* msg1  = (unsigned*)(xw + (size_t)N_NODES * 32);   // E*16 u32
    unsigned* msg2  = msg1 + (size_t)E_EDGES * 16;          // E*32 u32
    short*    wbt2  = (short*)(msg2 + (size_t)E_EDGES * 32);// 65536 f16
    short*    wbt1  = wbt2 + 65536;                         // 8192 f16
    short*    w1bt2 = wbt1 + 8192;                          // 1024 f16
    short*    w1bt1 = w1bt2 + 1024;                         // 1024 f16
    int*      deg   = (int*)(w1bt1 + 1024);                 // N
    int*      off   = deg + N_NODES;                        // N+1 (+pad)
    int*      cursor= off + N_NODES + 16;                   // N
    int*      perm  = cursor + N_NODES;                     // E
    int*      srcp  = perm + E_EDGES;                       // E
    float*    gwp   = (float*)(srcp + E_EDGES);             // E

    hipMemsetAsync(deg, 0, N_NODES * sizeof(int), stream);

    prep<<<E_EDGES / 256, 256, 0, stream>>>(e2_wk, e2_bk, e1_wk, e1_bk,
        e2_w1, e2_b1, e1_w1, e1_b1, tgt, wbt2, wbt1, w1bt2, w1bt1, deg);
    csr_scan<<<1, 1024, 0, stream>>>(deg, off, cursor);

    ecc1_mfma<<<E_EDGES / 256, 256, 0, stream>>>(x, e, src, tgt, gcn_w,
        e1_w0, e1_b0, w1bt1, wbt1, cursor, perm, srcp, gwp, msg1);
    gather1<<<N_NODES / 16, 256, 0, stream>>>(msg1, off, x, e1_root, e1_bias, x1);
    ecc2_mfma<<<E_EDGES / 256, 256, 0, stream>>>(x1, e, src, perm,
        e2_w0, e2_b0, w1bt2, wbt2, msg2);
    gather2<<<N_NODES / 8, 256, 0, stream>>>(msg2, off, x1,
        e2_root, e2_bias, gcn_W, xw, out);
    gcn_pool<<<N_NODES / 8, 256, 0, stream>>>(xw, off, srcp, gwp,
        gcn_w, gcn_b, seg, out);
}